// Round 6
// baseline (444.298 us; speedup 1.0000x reference)
//
#include <hip/hip_runtime.h>

using u16 = unsigned short;
using u32 = unsigned int;

typedef __attribute__((ext_vector_type(4))) float f32x4;
typedef __attribute__((ext_vector_type(8))) short frag8;   // 8 x bf16 (4 VGPRs)

#define HIDDEN 2048
#define SEQ    2048
#define NHEADS 16
#define HDIM   128

__device__ __forceinline__ float bf2f(u16 u) {
  union { u32 i; float f; } c; c.i = ((u32)u) << 16; return c.f;
}
__device__ __forceinline__ u16 f2bf(float f) {   // RNE
  union { float f; u32 i; } c; c.f = f;
  u32 u = c.i + 0x7fffu + ((c.i >> 16) & 1u);
  return (u16)(u >> 16);
}

// ---------------------------------------------------------------------------
// Fused f32 -> bf16 convert for X + 4 weight matrices, ONE dispatch.
// ---------------------------------------------------------------------------
__global__ void cvt_all(const float* __restrict__ X,
                        const float* __restrict__ W0, const float* __restrict__ W1,
                        const float* __restrict__ W2, const float* __restrict__ W3,
                        u16* __restrict__ dX,
                        u16* __restrict__ dW0, u16* __restrict__ dW1,
                        u16* __restrict__ dW2, u16* __restrict__ dW3)
{
  const int bx = blockIdx.x;
  const float* s; u16* d; int g;
  if (bx < 4096) { s = X; d = dX; g = bx * 256 + threadIdx.x; }
  else {
    const int t = bx - 4096;
    const int w = t >> 11;               // 0..3
    s = (w == 0) ? W0 : (w == 1) ? W1 : (w == 2) ? W2 : W3;
    d = (w == 0) ? dW0 : (w == 1) ? dW1 : (w == 2) ? dW2 : dW3;
    g = (t & 2047) * 256 + threadIdx.x;
  }
  const float* p = s + (size_t)g * 8;
  f32x4 x0 = *(const f32x4*)p, x1 = *(const f32x4*)(p + 4);
  frag8 o;
#pragma unroll
  for (int e = 0; e < 4; e++) { o[e] = (short)f2bf(x0[e]); o[e+4] = (short)f2bf(x1[e]); }
  *(frag8*)(d + (size_t)g * 8) = o;
}

// ---------------------------------------------------------------------------
// OLD 128x128 fused NT GEMM (kept for the slow path).
// ---------------------------------------------------------------------------
template<int W_BF16, int NW, int VT, int C_F32>
__global__ __launch_bounds__(256, 4)
void gemm_fused(const u16* __restrict__ A,
                const void* __restrict__ W0, const void* __restrict__ W1,
                const void* __restrict__ W2,
                const float* __restrict__ bias0, const float* __restrict__ bias1,
                const float* __restrict__ bias2,
                void* __restrict__ C0, void* __restrict__ C1, void* __restrict__ C2)
{
  __shared__ __align__(16) u16 smem[8192];     // As [0,4096), Bs [4096,8192)
  u16* As = smem;
  u16* Bs = smem + 4096;

  const int tid  = threadIdx.x;
  const int lane = tid & 63;
  const int wv   = tid >> 6;
  const int quad = lane >> 4;
  const int l16  = lane & 15;
  const int wm = wv >> 1, wn = wv & 1;
  const int m0 = blockIdx.y * 128;
  const int wix = (NW == 1) ? 0 : (blockIdx.x >> 4);
  const int n0  = ((NW == 1) ? blockIdx.x : (blockIdx.x & 15)) * 128;

  const void* Wp = (wix == 0) ? W0 : (wix == 1) ? W1 : W2;
  const float* bias = (wix == 0) ? bias0 : (wix == 1) ? bias1 : bias2;
  void* Cp = (wix == 0) ? C0 : (wix == 1) ? C1 : C2;

  f32x4 acc[4][4];
#pragma unroll
  for (int i = 0; i < 4; i++)
#pragma unroll
    for (int j = 0; j < 4; j++) acc[i][j] = (f32x4)0.0f;

  const int g0 = tid, g1 = tid + 256;
  const int r0 = g0 >> 2, c0 = (g0 & 3) * 8;
  const int r1 = g1 >> 2, c1 = (g1 & 3) * 8;

  for (int k0 = 0; k0 < HIDDEN; k0 += 32) {
    __builtin_amdgcn_global_load_lds(
      (const __attribute__((address_space(1))) void*)(A + (size_t)(m0 + r0) * HIDDEN + k0 + c0),
      (__attribute__((address_space(3))) void*)(As + g0 * 8), 16, 0, 0);
    __builtin_amdgcn_global_load_lds(
      (const __attribute__((address_space(1))) void*)(A + (size_t)(m0 + r1) * HIDDEN + k0 + c1),
      (__attribute__((address_space(3))) void*)(As + g1 * 8), 16, 0, 0);
    if (W_BF16) {
      const u16* Wb = (const u16*)Wp;
      __builtin_amdgcn_global_load_lds(
        (const __attribute__((address_space(1))) void*)(Wb + (size_t)(n0 + r0) * HIDDEN + k0 + c0),
        (__attribute__((address_space(3))) void*)(Bs + g0 * 8), 16, 0, 0);
      __builtin_amdgcn_global_load_lds(
        (const __attribute__((address_space(1))) void*)(Wb + (size_t)(n0 + r1) * HIDDEN + k0 + c1),
        (__attribute__((address_space(3))) void*)(Bs + g1 * 8), 16, 0, 0);
    } else {
      const float* Wf = (const float*)Wp;
      const float* p0 = Wf + (size_t)(n0 + r0) * HIDDEN + k0 + c0;
      const float* p1 = Wf + (size_t)(n0 + r1) * HIDDEN + k0 + c1;
      f32x4 x0 = *(const f32x4*)p0, x1 = *(const f32x4*)(p0 + 4);
      f32x4 y0 = *(const f32x4*)p1, y1 = *(const f32x4*)(p1 + 4);
      frag8 b0v, b1v;
#pragma unroll
      for (int e = 0; e < 4; e++) {
        b0v[e]   = (short)f2bf(x0[e]); b0v[e+4] = (short)f2bf(x1[e]);
        b1v[e]   = (short)f2bf(y0[e]); b1v[e+4] = (short)f2bf(y1[e]);
      }
      *(frag8*)&Bs[g0 * 8] = b0v;
      *(frag8*)&Bs[g1 * 8] = b1v;
    }

    __builtin_amdgcn_s_waitcnt(0);   // drain DMA before barrier
    __syncthreads();

    frag8 af[4], bfr[4];
#pragma unroll
    for (int mt = 0; mt < 4; mt++)
      af[mt] = *(const frag8*)&As[(wm*64 + mt*16 + l16) * 32 + quad*8];
#pragma unroll
    for (int nt = 0; nt < 4; nt++)
      bfr[nt] = *(const frag8*)&Bs[(wn*64 + nt*16 + l16) * 32 + quad*8];
#pragma unroll
    for (int mt = 0; mt < 4; mt++)
#pragma unroll
      for (int nt = 0; nt < 4; nt++)
        acc[mt][nt] = __builtin_amdgcn_mfma_f32_16x16x32_bf16(af[mt], bfr[nt], acc[mt][nt], 0, 0, 0);

    __syncthreads();
  }

  if (VT && wix == 2) {
    u16* Cv = (u16*)Cp;
    u16* T = smem + wv * 1056;
#pragma unroll
    for (int nt = 0; nt < 4; nt++) {
      const int n  = n0 + wn*64 + nt*16 + l16;
      const float bv = bias[n];
#pragma unroll
      for (int mt = 0; mt < 4; mt++)
#pragma unroll
        for (int r = 0; r < 4; r++)
          T[l16 * 66 + mt*16 + quad*4 + r] = f2bf(acc[mt][nt][r] + bv);
#pragma unroll
      for (int rr = 0; rr < 16; rr++) {
        const int nn = n0 + wn*64 + nt*16 + rr;
        const int mm = m0 + wm*64 + lane;
        const int b = mm >> 11, s = mm & 2047;
        Cv[((size_t)(b * HIDDEN + nn)) * SEQ + s] = T[rr * 66 + lane];
      }
    }
  } else {
#pragma unroll
    for (int nt = 0; nt < 4; nt++) {
      const int n  = n0 + wn*64 + nt*16 + l16;
      const float bv = bias[n];
#pragma unroll
      for (int mt = 0; mt < 4; mt++) {
#pragma unroll
        for (int r = 0; r < 4; r++) {
          const int m = m0 + wm*64 + mt*16 + quad*4 + r;
          if (C_F32) ((float*)Cp)[(size_t)m * HIDDEN + n] = acc[mt][nt][r] + bv;
          else       ((u16*)Cp)[(size_t)m * HIDDEN + n]   = f2bf(acc[mt][nt][r] + bv);
        }
      }
    }
  }
}

// ---------------------------------------------------------------------------
// Deep-pipelined GEMM core (T1+T2+T3+T4+T5): tile 256(M) x 128(N), BK=64,
// 512 thr = 8 waves (2M x 4N).  3 LDS buffers, staged 2 K-tiles ahead,
// counted vmcnt(6).  Shared by gemm256_qkv and gemm256_o.
// ---------------------------------------------------------------------------
#define NT32 32   // 2048 / 64 K-tiles

#define STG(gptr, lofs) __builtin_amdgcn_global_load_lds( \
    (const __attribute__((address_space(1))) void*)(gptr), \
    (__attribute__((address_space(3))) void*)(smem + (lofs)), 16, 0, 0)

#define GRP(t, DOSTAGE, WAITSTR) { \
  u16* As = smem + ((t) % 3) * 24576; \
  u16* Bs = As + 16384; \
  frag8 af[8], bfr[2]; \
  _Pragma("unroll") for (int mt = 0; mt < 8; mt++) \
    af[mt] = *(const frag8*)(As + abase + mt*1024 + s0q); \
  bfr[0] = *(const frag8*)(Bs + bbase + s0q); \
  bfr[1] = *(const frag8*)(Bs + bbase + 1024 + s0q); \
  if (DOSTAGE) { \
    const size_t ko = (size_t)((t)+2)*64; const int sb = (((t)+2)%3)*24576; \
    STG(gA0 + ko, sb + ldsA0); STG(gA1 + ko, sb + ldsA1); STG(gB0 + ko, sb + ldsB0); \
  } \
  __builtin_amdgcn_s_barrier(); \
  __builtin_amdgcn_s_setprio(1); \
  _Pragma("unroll") for (int mt = 0; mt < 8; mt++) { \
    acc[mt][0] = __builtin_amdgcn_mfma_f32_16x16x32_bf16(af[mt], bfr[0], acc[mt][0], 0,0,0); \
    acc[mt][1] = __builtin_amdgcn_mfma_f32_16x16x32_bf16(af[mt], bfr[1], acc[mt][1], 0,0,0); \
  } \
  __builtin_amdgcn_s_setprio(0); \
  __builtin_amdgcn_s_barrier(); \
  _Pragma("unroll") for (int mt = 0; mt < 8; mt++) \
    af[mt] = *(const frag8*)(As + abase + mt*1024 + s1q); \
  bfr[0] = *(const frag8*)(Bs + bbase + s1q); \
  bfr[1] = *(const frag8*)(Bs + bbase + 1024 + s1q); \
  if (DOSTAGE) { \
    const size_t ko = (size_t)((t)+2)*64; const int sb = (((t)+2)%3)*24576; \
    STG(gA2 + ko, sb + ldsA2); STG(gA3 + ko, sb + ldsA3); STG(gB1 + ko, sb + ldsB1); \
  } \
  __builtin_amdgcn_s_barrier(); \
  __builtin_amdgcn_s_setprio(1); \
  _Pragma("unroll") for (int mt = 0; mt < 8; mt++) { \
    acc[mt][0] = __builtin_amdgcn_mfma_f32_16x16x32_bf16(af[mt], bfr[0], acc[mt][0], 0,0,0); \
    acc[mt][1] = __builtin_amdgcn_mfma_f32_16x16x32_bf16(af[mt], bfr[1], acc[mt][1], 0,0,0); \
  } \
  __builtin_amdgcn_s_setprio(0); \
  asm volatile("s_waitcnt " WAITSTR ::: "memory"); \
  __builtin_amdgcn_s_barrier(); \
}

// common per-thread setup for the 256x128 core (defines all names GRP needs)
#define G256_SETUP(Abase, Wbase) \
  const int tid  = threadIdx.x; \
  const int lane = tid & 63; \
  const int wv   = tid >> 6; \
  const int quad = lane >> 4; \
  const int l16  = lane & 15; \
  const int wm = wv >> 2, wn = wv & 3; \
  const int c8 = (lane & 7) ^ (lane >> 3); \
  const int rA = lane >> 3; \
  const u16* gA0 = (Abase) + (size_t)(m0 + wv*32 +  0 + rA) * HIDDEN + c8*8; \
  const u16* gA1 = (Abase) + (size_t)(m0 + wv*32 +  8 + rA) * HIDDEN + c8*8; \
  const u16* gA2 = (Abase) + (size_t)(m0 + wv*32 + 16 + rA) * HIDDEN + c8*8; \
  const u16* gA3 = (Abase) + (size_t)(m0 + wv*32 + 24 + rA) * HIDDEN + c8*8; \
  const u16* gB0 = (Wbase) + (size_t)(n0 + wv*16 +  0 + rA) * HIDDEN + c8*8; \
  const u16* gB1 = (Wbase) + (size_t)(n0 + wv*16 +  8 + rA) * HIDDEN + c8*8; \
  const int ldsA0 = (4*wv)*512 + lane*8; \
  const int ldsA1 = ldsA0 + 512; \
  const int ldsA2 = ldsA0 + 1024; \
  const int ldsA3 = ldsA0 + 1536; \
  const int ldsB0 = 16384 + (2*wv)*512 + lane*8; \
  const int ldsB1 = ldsB0 + 512; \
  const int s0q = ((quad    ) ^ (l16 & 7)) * 8; \
  const int s1q = ((quad + 4) ^ (l16 & 7)) * 8; \
  const int abase = (wm*128 + l16) * 64; \
  const int bbase = (wn*32  + l16) * 64; \
  f32x4 acc[8][2]; \
  _Pragma("unroll") \
  for (int i = 0; i < 8; i++) { acc[i][0] = (f32x4)0.0f; acc[i][1] = (f32x4)0.0f; } \
  STG(gA0, ldsA0); STG(gA1, ldsA1); STG(gB0, ldsB0); \
  STG(gA2, ldsA2); STG(gA3, ldsA3); STG(gB1, ldsB1); \
  STG(gA0 + 64, 24576 + ldsA0); STG(gA1 + 64, 24576 + ldsA1); STG(gB0 + 64, 24576 + ldsB0); \
  STG(gA2 + 64, 24576 + ldsA2); STG(gA3 + 64, 24576 + ldsA3); STG(gB1 + 64, 24576 + ldsB1); \
  asm volatile("s_waitcnt vmcnt(6)" ::: "memory"); \
  __builtin_amdgcn_s_barrier(); \
  for (int t = 0; t < NT32 - 2; ++t) GRP(t, 1, "vmcnt(6)"); \
  GRP(NT32 - 2, 0, "vmcnt(0)"); \
  GRP(NT32 - 1, 0, "vmcnt(63)");

// --- QKV: grid 768 (48 colTiles x 16 rowTiles), bf16 C; wix==2 -> Vt store.
__global__ __launch_bounds__(512, 2)
void gemm256_qkv(const u16* __restrict__ A,
                 const u16* __restrict__ W0, const u16* __restrict__ W1,
                 const u16* __restrict__ W2,
                 const float* __restrict__ bias0, const float* __restrict__ bias1,
                 const float* __restrict__ bias2,
                 u16* __restrict__ C0, u16* __restrict__ C1, u16* __restrict__ Vt)
{
  __shared__ __align__(16) u16 smem[73728];   // 144 KiB

  const int bid = blockIdx.x;
  const int sbid = (bid & 7) * 96 + (bid >> 3);   // 768 % 8 == 0, bijective
  const int colTile = sbid >> 4;        // 0..47
  const int rowTile = sbid & 15;        // 0..15
  const int wix = colTile >> 4;         // 0:Q 1:K 2:V
  const int n0  = (colTile & 15) * 128;
  const int m0  = rowTile * 256;

  const u16* Wp = (wix == 0) ? W0 : (wix == 1) ? W1 : W2;
  const float* bias = (wix == 0) ? bias0 : (wix == 1) ? bias1 : bias2;

  G256_SETUP(A, Wp)

  if (wix != 2) {
    u16* Cb = (wix == 0) ? C0 : C1;
#pragma unroll
    for (int nt = 0; nt < 2; nt++) {
      const int n = n0 + wn*32 + nt*16 + l16;
      const float bv = bias[n];
#pragma unroll
      for (int mt = 0; mt < 8; mt++) {
        const int m = m0 + wm*128 + mt*16 + quad*4;
#pragma unroll
        for (int r = 0; r < 4; r++)
          Cb[(size_t)(m + r) * HIDDEN + n] = f2bf(acc[mt][nt][r] + bv);
      }
    }
  } else {
    u16* T = smem + wv * 2176;         // 16 x 136 u16 per wave
    const int b  = m0 >> 11;
    const int s0 = (m0 & 2047) + wm*128;
#pragma unroll
    for (int nt = 0; nt < 2; nt++) {
      const int nloc = n0 + wn*32 + nt*16;
      const float bv = bias[nloc + l16];
#pragma unroll
      for (int mt = 0; mt < 8; mt++)
#pragma unroll
        for (int r = 0; r < 4; r++)
          T[l16*136 + mt*16 + quad*4 + r] = f2bf(acc[mt][nt][r] + bv);
#pragma unroll
      for (int rr = 0; rr < 16; rr++) {
        const size_t vb = ((size_t)(b * HIDDEN + nloc + rr)) * SEQ + s0;
        Vt[vb + lane]      = T[rr*136 + lane];
        Vt[vb + 64 + lane] = T[rr*136 + 64 + lane];
      }
    }
  }
}

// --- out-proj: grid 256 (16 colTiles x 16 rowTiles), f32 C.
__global__ __launch_bounds__(512, 2)
void gemm256_o(const u16* __restrict__ A, const u16* __restrict__ W,
               const float* __restrict__ bias, float* __restrict__ C)
{
  __shared__ __align__(16) u16 smem[73728];   // 144 KiB

  const int bid = blockIdx.x;
  const int sbid = (bid & 7) * 32 + (bid >> 3);   // 256 % 8 == 0, bijective
  const int colTile = sbid >> 4;        // 0..15
  const int rowTile = sbid & 15;        // 0..15
  const int n0  = colTile * 128;
  const int m0  = rowTile * 256;

  G256_SETUP(A, W)

#pragma unroll
  for (int nt = 0; nt < 2; nt++) {
    const int n = n0 + wn*32 + nt*16 + l16;
    const float bv = bias[n];
#pragma unroll
    for (int mt = 0; mt < 8; mt++) {
      const int m = m0 + wm*128 + mt*16 + quad*4;
#pragma unroll
      for (int r = 0; r < 4; r++)
        C[(size_t)(m + r) * HIDDEN + n] = acc[mt][nt][r] + bv;
    }
  }
}

// ---------------------------------------------------------------------------
// RoPE in place on bf16 Q,K; 8 d/thread.  Q pre-scaled by 1/sqrt(128).
// ---------------------------------------------------------------------------
__global__ void rope_kernel(u16* __restrict__ Q, u16* __restrict__ K)
{
  const int tid = blockIdx.x * 256 + threadIdx.x;   // 2^20 total
  const int t   = tid >> 19;           // 0:Q 1:K
  const int r   = tid & 524287;
  const int row = r >> 7;              // [0,4096)
  const int grp = r & 127;
  const int h   = grp >> 3, d0 = (grp & 7) * 8;
  u16* X = t ? K : Q;
  const float s = (float)(row & 2047);
  const float qscale = t ? 1.0f : 0.08838834764831845f;
  const size_t base = (size_t)row * HIDDEN + h * HDIM + d0;
  frag8 a = *(const frag8*)(X + base);
  frag8 b = *(const frag8*)(X + base + 64);
  frag8 oa, ob;
#pragma unroll
  for (int e = 0; e < 8; e++) {
    const float inv = __expf(-(float)(d0 + e) * (9.210340371976184f / 64.0f));
    float sn, c;
    __sincosf(s * inv, &sn, &c);
    const float x1 = bf2f((u16)a[e]), x2 = bf2f((u16)b[e]);
    oa[e] = (short)f2bf((x1 * c - x2 * sn) * qscale);
    ob[e] = (short)f2bf((x2 * c + x1 * sn) * qscale);
  }
  *(frag8*)(X + base)      = oa;
  *(frag8*)(X + base + 64) = ob;
}

// ---------------------------------------------------------------------------
// Flash attention (causal) — 64-q tile, occupancy-first.
// Grid 1024 = 32 qt x 32 bh (zigzag).  Block 256 thr = 4 waves, 16 q/wave.
// K/V staged via global_load_lds (serial: stage -> vmcnt(0) -> barrier),
// swizzled layouts (T2, round-4-proven geometry); P also swizzled.
// LDS exactly 40960 B -> 4 blocks/CU (16 waves/CU).  T13 defer-max, T5 setprio.
// LDS u16: Ks [0,8192)=[64][128] swz | Vs [8192,16384)=[128][64] swz |
//          Ps [16384,20480) per-wave [16][64] swz.
// ---------------------------------------------------------------------------
__global__ __launch_bounds__(256, 4)
void attn_kernel(const u16* Q, const u16* __restrict__ K,
                 const u16* __restrict__ Vt, u16* O)
{
  __shared__ __align__(16) u16 smem[20480];   // 40 KiB exactly

  const int bx = blockIdx.x;
  const int g  = bx >> 5;                 // [0,32)
  const int bh = bx & 31;
  const int qt = (g & 1) ? (31 - (g >> 1)) : (g >> 1);   // zigzag balance
  const int b = bh >> 4, h = bh & 15;

  const int tid = threadIdx.x, lane = tid & 63, wv = tid >> 6;
  const int quad = lane >> 4, l16 = lane & 15;
  const int l7 = l16 & 7;

  const size_t krow0 = (size_t)(b * SEQ) * HIDDEN + h * HDIM;
  const size_t vrow0 = (size_t)(b * HIDDEN + h * HDIM) * SEQ;

  // Q A-fragments: lane holds Q[m = l16][d = ks*32 + quad*8 + j]
  frag8 qf[4];
  const size_t qbase = ((size_t)(b * SEQ) + qt*64 + wv*16) * HIDDEN + h * HDIM;
#pragma unroll
  for (int ks = 0; ks < 4; ks++)
    qf[ks] = *(const frag8*)(Q + qbase + (size_t)l16 * HIDDEN + ks*32 + quad*8);

  // DMA staging addresses (round-4-proven geometry).
  // K: per inst 4 rows x 256B; lane -> row (lane>>4), slot (lane&15); src slot ^= row&7.
  // V: per inst 8 rows x 128B; lane -> row (lane>>3), slot (lane&7); src slot ^= row&7.
  const int kr4 = lane >> 4, kc = lane & 15;
  const int vr8 = lane >> 3;
  const u16* gK[4]; const u16* gV[4];
  int ldsK[4], ldsV[4];
#pragma unroll
  for (int it = 0; it < 4; it++) {
    const int kcs = kc ^ ((it*4 + kr4) & 7);
    gK[it] = K + krow0 + (size_t)(wv*16 + it*4 + kr4) * HIDDEN + kcs*8;
    ldsK[it] = (wv*16 + it*4)*128 + lane*8;
    const int vcs = (lane & 7) ^ vr8;
    gV[it] = Vt + vrow0 + (size_t)(wv*32 + it*8 + vr8) * SEQ + vcs*8;
    ldsV[it] = 8192 + (wv*32 + it*8)*64 + lane*8;
  }

  f32x4 Oacc[8];
#pragma unroll
  for (int dt = 0; dt < 8; dt++) Oacc[dt] = (f32x4)0.0f;
  float m_i[4], l_i[4];
#pragma unroll
  for (int r = 0; r < 4; r++) { m_i[r] = -1e30f; l_i[r] = 0.0f; }

  const int ktmax = qt + 1;
  u16* Pw = smem + 16384 + wv*1024;   // this wave's P: [16][64] swizzled

  for (int kt = 0; kt < ktmax; kt++) {
    // ---- stage K tile [64][128] + V tile [128][64] via DMA (serial)
#pragma unroll
    for (int it = 0; it < 4; it++) {
      __builtin_amdgcn_global_load_lds(
        (const __attribute__((address_space(1))) void*)(gK[it] + (size_t)kt*64*HIDDEN),
        (__attribute__((address_space(3))) void*)(smem + ldsK[it]), 16, 0, 0);
      __builtin_amdgcn_global_load_lds(
        (const __attribute__((address_space(1))) void*)(gV[it] + kt*64),
        (__attribute__((address_space(3))) void*)(smem + ldsV[it]), 16, 0, 0);
    }
    asm volatile("s_waitcnt vmcnt(0)" ::: "memory");
    __syncthreads();

    // ---- S = Q*K^T : 16 queries x 64 keys (Q pre-scaled), swizzled K reads
    f32x4 st[4];
#pragma unroll
    for (int jt = 0; jt < 4; jt++) st[jt] = (f32x4)0.0f;

    __builtin_amdgcn_s_setprio(1);
#pragma unroll
    for (int ks = 0; ks < 4; ks++) {
      frag8 kf[4];
#pragma unroll
      for (int jt = 0; jt < 4; jt++)
        kf[jt] = *(const frag8*)&smem[(jt*16 + l16)*128 + ((ks*4 + quad) ^ l7)*8];
#pragma unroll
      for (int jt = 0; jt < 4; jt++)
        st[jt] = __builtin_amdgcn_mfma_f32_16x16x32_bf16(qf[ks], kf[jt], st[jt], 0, 0, 0);
    }
    __builtin_amdgcn_s_setprio(0);

    // ---- causal mask on the diagonal tile only
    if (kt == qt) {
#pragma unroll
      for (int jt = 0; jt < 4; jt++) {
        const int jl = jt*16 + l16;
#pragma unroll
        for (int r = 0; r < 4; r++) {
          const int ml = wv*16 + quad*4 + r;
          st[jt][r] = (jl <= ml) ? st[jt][r] : -1e30f;
        }
      }
    }

    // ---- online softmax; T13 defer-max (THR=8)
    float alpha[4];
    int needresc = 0;
#pragma unroll
    for (int r = 0; r < 4; r++) {
      float cm = fmaxf(fmaxf(st[0][r], st[1][r]), fmaxf(st[2][r], st[3][r]));
      cm = fmaxf(cm, __shfl_xor(cm, 1, 64));
      cm = fmaxf(cm, __shfl_xor(cm, 2, 64));
      cm = fmaxf(cm, __shfl_xor(cm, 4, 64));
      cm = fmaxf(cm, __shfl_xor(cm, 8, 64));
      if (cm > m_i[r] + 8.0f) {
        alpha[r] = __expf(m_i[r] - cm);
        m_i[r] = cm;
        needresc = 1;
      } else {
        alpha[r] = 1.0f;
      }
    }

    // ---- p = exp(s - m); P -> LDS (swizzled: slot ^= row&7); row sums
    float csum[4];
#pragma unroll
    for (int r = 0; r < 4; r++) csum[r] = 0.0f;
#pragma unroll
    for (int jt = 0; jt < 4; jt++)
#pragma unroll
      for (int r = 0; r < 4; r++) {
        const float p = __expf(st[jt][r] - m_i[r]);
        csum[r] += p;
        const int prow = quad*4 + r;
        Pw[prow*64 + (((jt*2 + (l16 >> 3)) ^ (prow & 7)) << 3) + l7] = f2bf(p);
      }
#pragma unroll
    for (int r = 0; r < 4; r++) {
      float cs = csum[r];
      cs += __shfl_xor(cs, 1, 64);
      cs += __shfl_xor(cs, 2, 64);
      cs += __shfl_xor(cs, 4, 64);
      cs += __shfl_xor(cs, 8, 64);
      l_i[r] = l_i[r] * alpha[r] + cs;
    }
    if (__any(needresc)) {
#pragma unroll
      for (int r = 0; r < 4; r++)
#pragma unroll
        for (int dt = 0; dt < 8; dt++) Oacc[dt][r] *= alpha[r];
    }

    // ---- O += P * V  (same-wave LDS RAW on Pw; swizzled P and V reads)
    __builtin_amdgcn_s_setprio(1);
#pragma unroll
    for (int ks2 = 0; ks2 < 2; ks2++) {
      frag8 pf = *(const frag8*)&Pw[l16*64 + ((ks2*4 + quad) ^ l7)*8];
#pragma unroll
      for (int dt = 0; dt < 8; dt++) {
        frag8 vf = *(const frag8*)&smem[8192 + (dt*16 + l16)*64 + ((ks2*4 + quad) ^ l7)*8];
        Oacc[dt] = __builtin_amdgcn_mfma_f32_16x16x32_bf16(pf, vf, Oacc[dt], 0, 0, 0);
      }
    }
    __builtin_amdgcn_s_setprio(0);
    __syncthreads();   // protect Ks/Vs before next stage
  }

  // ---- finalize: /l_i, store merged [b*2048+m][h*128+d]
#pragma unroll
  for (int r = 0; r < 4; r++) {
    const float inv = 1.0f / l_i[r];
    const int m = qt*64 + wv*16 + quad*4 + r;
#pragma unroll
    for (int dt = 0; dt < 8; dt++) {
      const int d = dt*16 + l16;
      O[((size_t)(b * SEQ) + m) * HIDDEN + h * HDIM + d] = f2bf(Oacc[dt][r] * inv);
    }
  }
}

// ---------------------------------------------------------------------------
extern "C" void kernel_launch(void* const* d_in, const int* in_sizes, int n_in,
                              void* d_out, int out_size, void* d_ws, size_t ws_size,
                              hipStream_t stream)
{
  const float* X  = (const float*)d_in[0];
  const float* Wq = (const float*)d_in[1];
  const float* bq = (const float*)d_in[2];
  const float* Wk = (const float*)d_in[3];
  const float* bk = (const float*)d_in[4];
  const float* Wv = (const float*)d_in[5];
  const float* bv = (const float*)d_in[6];
  const float* Wo = (const float*)d_in[7];
  const float* bo = (const float*)d_in[8];
  float* out = (float*)d_out;

  u16* Kb = (u16*)d_out;
  u16* Xb = (u16*)d_out + (8u << 20);
  char* ws = (char*)d_ws;
  u16* Qb  = (u16*)ws;
  u16* Vtb = (u16*)(ws + (16u << 20));

  dim3 blk(256);
  const bool fast = ws_size >= (64u << 20);
  if (fast) {
    u16* Wqb = (u16*)(ws + (32u << 20));
    u16* Wkb = (u16*)(ws + (40u << 20));
    u16* Wvb = (u16*)(ws + (48u << 20));
    u16* Wob = (u16*)(ws + (56u << 20));
    cvt_all<<<12288, blk, 0, stream>>>(X, Wq, Wk, Wv, Wo, Xb, Wqb, Wkb, Wvb, Wob);
    gemm256_qkv<<<dim3(768), dim3(512), 0, stream>>>(
        Xb, Wqb, Wkb, Wvb, bq, bk, bv, Qb, Kb, Vtb);
    rope_kernel<<<4096, blk, 0, stream>>>(Qb, Kb);
    attn_kernel<<<1024, blk, 0, stream>>>(Qb, Kb, Vtb, Qb);
    gemm256_o<<<dim3(256), dim3(512), 0, stream>>>(Qb, Wob, bo, out);
  } else {
    cvt_all<<<4096, blk, 0, stream>>>(X, Wq, Wk, Wv, Wo, Xb, Xb, Xb, Xb, Xb);
    gemm_fused<0,3,1,0><<<dim3(48,32), blk, 0, stream>>>(
        Xb, Wq, Wk, Wv, bq, bk, bv, Qb, Kb, Vtb);
    rope_kernel<<<4096, blk, 0, stream>>>(Qb, Kb);
    attn_kernel<<<1024, blk, 0, stream>>>(Qb, Kb, Vtb, Qb);
    gemm_fused<0,1,0,1><<<dim3(16,32), blk, 0, stream>>>(
        Qb, Wo, Wo, Wo, bo, bo, bo, out, out, out);
  }
}

// Round 7
// 430.200 us; speedup vs baseline: 1.0328x; 1.0328x over previous
//
#include <hip/hip_runtime.h>

using u16 = unsigned short;
using u32 = unsigned int;

typedef __attribute__((ext_vector_type(4))) float f32x4;
typedef __attribute__((ext_vector_type(8))) short frag8;   // 8 x bf16 (4 VGPRs)

#define HIDDEN 2048
#define SEQ    2048
#define NHEADS 16
#define HDIM   128

__device__ __forceinline__ float bf2f(u16 u) {
  union { u32 i; float f; } c; c.i = ((u32)u) << 16; return c.f;
}
__device__ __forceinline__ u16 f2bf(float f) {   // RNE
  union { float f; u32 i; } c; c.f = f;
  u32 u = c.i + 0x7fffu + ((c.i >> 16) & 1u);
  return (u16)(u >> 16);
}

// ---------------------------------------------------------------------------
// Fused f32 -> bf16 convert for X + 4 weight matrices, ONE dispatch.
// ---------------------------------------------------------------------------
__global__ void cvt_all(const float* __restrict__ X,
                        const float* __restrict__ W0, const float* __restrict__ W1,
                        const float* __restrict__ W2, const float* __restrict__ W3,
                        u16* __restrict__ dX,
                        u16* __restrict__ dW0, u16* __restrict__ dW1,
                        u16* __restrict__ dW2, u16* __restrict__ dW3)
{
  const int bx = blockIdx.x;
  const float* s; u16* d; int g;
  if (bx < 4096) { s = X; d = dX; g = bx * 256 + threadIdx.x; }
  else {
    const int t = bx - 4096;
    const int w = t >> 11;               // 0..3
    s = (w == 0) ? W0 : (w == 1) ? W1 : (w == 2) ? W2 : W3;
    d = (w == 0) ? dW0 : (w == 1) ? dW1 : (w == 2) ? dW2 : dW3;
    g = (t & 2047) * 256 + threadIdx.x;
  }
  const float* p = s + (size_t)g * 8;
  f32x4 x0 = *(const f32x4*)p, x1 = *(const f32x4*)(p + 4);
  frag8 o;
#pragma unroll
  for (int e = 0; e < 4; e++) { o[e] = (short)f2bf(x0[e]); o[e+4] = (short)f2bf(x1[e]); }
  *(frag8*)(d + (size_t)g * 8) = o;
}

// ---------------------------------------------------------------------------
// OLD 128x128 fused NT GEMM (kept for the slow path).
// ---------------------------------------------------------------------------
template<int W_BF16, int NW, int VT, int C_F32>
__global__ __launch_bounds__(256, 4)
void gemm_fused(const u16* __restrict__ A,
                const void* __restrict__ W0, const void* __restrict__ W1,
                const void* __restrict__ W2,
                const float* __restrict__ bias0, const float* __restrict__ bias1,
                const float* __restrict__ bias2,
                void* __restrict__ C0, void* __restrict__ C1, void* __restrict__ C2)
{
  __shared__ __align__(16) u16 smem[8192];     // As [0,4096), Bs [4096,8192)
  u16* As = smem;
  u16* Bs = smem + 4096;

  const int tid  = threadIdx.x;
  const int lane = tid & 63;
  const int wv   = tid >> 6;
  const int quad = lane >> 4;
  const int l16  = lane & 15;
  const int wm = wv >> 1, wn = wv & 1;
  const int m0 = blockIdx.y * 128;
  const int wix = (NW == 1) ? 0 : (blockIdx.x >> 4);
  const int n0  = ((NW == 1) ? blockIdx.x : (blockIdx.x & 15)) * 128;

  const void* Wp = (wix == 0) ? W0 : (wix == 1) ? W1 : W2;
  const float* bias = (wix == 0) ? bias0 : (wix == 1) ? bias1 : bias2;
  void* Cp = (wix == 0) ? C0 : (wix == 1) ? C1 : C2;

  f32x4 acc[4][4];
#pragma unroll
  for (int i = 0; i < 4; i++)
#pragma unroll
    for (int j = 0; j < 4; j++) acc[i][j] = (f32x4)0.0f;

  const int g0 = tid, g1 = tid + 256;
  const int r0 = g0 >> 2, c0 = (g0 & 3) * 8;
  const int r1 = g1 >> 2, c1 = (g1 & 3) * 8;

  for (int k0 = 0; k0 < HIDDEN; k0 += 32) {
    __builtin_amdgcn_global_load_lds(
      (const __attribute__((address_space(1))) void*)(A + (size_t)(m0 + r0) * HIDDEN + k0 + c0),
      (__attribute__((address_space(3))) void*)(As + g0 * 8), 16, 0, 0);
    __builtin_amdgcn_global_load_lds(
      (const __attribute__((address_space(1))) void*)(A + (size_t)(m0 + r1) * HIDDEN + k0 + c1),
      (__attribute__((address_space(3))) void*)(As + g1 * 8), 16, 0, 0);
    if (W_BF16) {
      const u16* Wb = (const u16*)Wp;
      __builtin_amdgcn_global_load_lds(
        (const __attribute__((address_space(1))) void*)(Wb + (size_t)(n0 + r0) * HIDDEN + k0 + c0),
        (__attribute__((address_space(3))) void*)(Bs + g0 * 8), 16, 0, 0);
      __builtin_amdgcn_global_load_lds(
        (const __attribute__((address_space(1))) void*)(Wb + (size_t)(n0 + r1) * HIDDEN + k0 + c1),
        (__attribute__((address_space(3))) void*)(Bs + g1 * 8), 16, 0, 0);
    } else {
      const float* Wf = (const float*)Wp;
      const float* p0 = Wf + (size_t)(n0 + r0) * HIDDEN + k0 + c0;
      const float* p1 = Wf + (size_t)(n0 + r1) * HIDDEN + k0 + c1;
      f32x4 x0 = *(const f32x4*)p0, x1 = *(const f32x4*)(p0 + 4);
      f32x4 y0 = *(const f32x4*)p1, y1 = *(const f32x4*)(p1 + 4);
      frag8 b0v, b1v;
#pragma unroll
      for (int e = 0; e < 4; e++) {
        b0v[e]   = (short)f2bf(x0[e]); b0v[e+4] = (short)f2bf(x1[e]);
        b1v[e]   = (short)f2bf(y0[e]); b1v[e+4] = (short)f2bf(y1[e]);
      }
      *(frag8*)&Bs[g0 * 8] = b0v;
      *(frag8*)&Bs[g1 * 8] = b1v;
    }

    __builtin_amdgcn_s_waitcnt(0);   // drain DMA before barrier
    __syncthreads();

    frag8 af[4], bfr[4];
#pragma unroll
    for (int mt = 0; mt < 4; mt++)
      af[mt] = *(const frag8*)&As[(wm*64 + mt*16 + l16) * 32 + quad*8];
#pragma unroll
    for (int nt = 0; nt < 4; nt++)
      bfr[nt] = *(const frag8*)&Bs[(wn*64 + nt*16 + l16) * 32 + quad*8];
#pragma unroll
    for (int mt = 0; mt < 4; mt++)
#pragma unroll
      for (int nt = 0; nt < 4; nt++)
        acc[mt][nt] = __builtin_amdgcn_mfma_f32_16x16x32_bf16(af[mt], bfr[nt], acc[mt][nt], 0, 0, 0);

    __syncthreads();
  }

  if (VT && wix == 2) {
    u16* Cv = (u16*)Cp;
    u16* T = smem + wv * 1056;
#pragma unroll
    for (int nt = 0; nt < 4; nt++) {
      const int n  = n0 + wn*64 + nt*16 + l16;
      const float bv = bias[n];
#pragma unroll
      for (int mt = 0; mt < 4; mt++)
#pragma unroll
        for (int r = 0; r < 4; r++)
          T[l16 * 66 + mt*16 + quad*4 + r] = f2bf(acc[mt][nt][r] + bv);
#pragma unroll
      for (int rr = 0; rr < 16; rr++) {
        const int nn = n0 + wn*64 + nt*16 + rr;
        const int mm = m0 + wm*64 + lane;
        const int b = mm >> 11, s = mm & 2047;
        Cv[((size_t)(b * HIDDEN + nn)) * SEQ + s] = T[rr * 66 + lane];
      }
    }
  } else {
#pragma unroll
    for (int nt = 0; nt < 4; nt++) {
      const int n  = n0 + wn*64 + nt*16 + l16;
      const float bv = bias[n];
#pragma unroll
      for (int mt = 0; mt < 4; mt++) {
#pragma unroll
        for (int r = 0; r < 4; r++) {
          const int m = m0 + wm*64 + mt*16 + quad*4 + r;
          if (C_F32) ((float*)Cp)[(size_t)m * HIDDEN + n] = acc[mt][nt][r] + bv;
          else       ((u16*)Cp)[(size_t)m * HIDDEN + n]   = f2bf(acc[mt][nt][r] + bv);
        }
      }
    }
  }
}

// ---------------------------------------------------------------------------
// Deep-pipelined GEMM core (T1+T2+T3+T4+T5): tile 256(M) x 128(N), BK=64,
// 512 thr = 8 waves (2M x 4N).  3 LDS buffers, staged 2 K-tiles ahead,
// counted vmcnt(6).  Shared by gemm256_qkv and gemm256_o.
// ---------------------------------------------------------------------------
#define NT32 32   // 2048 / 64 K-tiles

#define STG(gptr, lofs) __builtin_amdgcn_global_load_lds( \
    (const __attribute__((address_space(1))) void*)(gptr), \
    (__attribute__((address_space(3))) void*)(smem + (lofs)), 16, 0, 0)

#define GRP(t, DOSTAGE, WAITSTR) { \
  u16* As = smem + ((t) % 3) * 24576; \
  u16* Bs = As + 16384; \
  frag8 af[8], bfr[2]; \
  _Pragma("unroll") for (int mt = 0; mt < 8; mt++) \
    af[mt] = *(const frag8*)(As + abase + mt*1024 + s0q); \
  bfr[0] = *(const frag8*)(Bs + bbase + s0q); \
  bfr[1] = *(const frag8*)(Bs + bbase + 1024 + s0q); \
  if (DOSTAGE) { \
    const size_t ko = (size_t)((t)+2)*64; const int sb = (((t)+2)%3)*24576; \
    STG(gA0 + ko, sb + ldsA0); STG(gA1 + ko, sb + ldsA1); STG(gB0 + ko, sb + ldsB0); \
  } \
  __builtin_amdgcn_s_barrier(); \
  __builtin_amdgcn_s_setprio(1); \
  _Pragma("unroll") for (int mt = 0; mt < 8; mt++) { \
    acc[mt][0] = __builtin_amdgcn_mfma_f32_16x16x32_bf16(af[mt], bfr[0], acc[mt][0], 0,0,0); \
    acc[mt][1] = __builtin_amdgcn_mfma_f32_16x16x32_bf16(af[mt], bfr[1], acc[mt][1], 0,0,0); \
  } \
  __builtin_amdgcn_s_setprio(0); \
  __builtin_amdgcn_s_barrier(); \
  _Pragma("unroll") for (int mt = 0; mt < 8; mt++) \
    af[mt] = *(const frag8*)(As + abase + mt*1024 + s1q); \
  bfr[0] = *(const frag8*)(Bs + bbase + s1q); \
  bfr[1] = *(const frag8*)(Bs + bbase + 1024 + s1q); \
  if (DOSTAGE) { \
    const size_t ko = (size_t)((t)+2)*64; const int sb = (((t)+2)%3)*24576; \
    STG(gA2 + ko, sb + ldsA2); STG(gA3 + ko, sb + ldsA3); STG(gB1 + ko, sb + ldsB1); \
  } \
  __builtin_amdgcn_s_barrier(); \
  __builtin_amdgcn_s_setprio(1); \
  _Pragma("unroll") for (int mt = 0; mt < 8; mt++) { \
    acc[mt][0] = __builtin_amdgcn_mfma_f32_16x16x32_bf16(af[mt], bfr[0], acc[mt][0], 0,0,0); \
    acc[mt][1] = __builtin_amdgcn_mfma_f32_16x16x32_bf16(af[mt], bfr[1], acc[mt][1], 0,0,0); \
  } \
  __builtin_amdgcn_s_setprio(0); \
  asm volatile("s_waitcnt " WAITSTR ::: "memory"); \
  __builtin_amdgcn_s_barrier(); \
}

// common per-thread setup for the 256x128 core (defines all names GRP needs)
#define G256_SETUP(Abase, Wbase) \
  const int tid  = threadIdx.x; \
  const int lane = tid & 63; \
  const int wv   = tid >> 6; \
  const int quad = lane >> 4; \
  const int l16  = lane & 15; \
  const int wm = wv >> 2, wn = wv & 3; \
  const int c8 = (lane & 7) ^ (lane >> 3); \
  const int rA = lane >> 3; \
  const u16* gA0 = (Abase) + (size_t)(m0 + wv*32 +  0 + rA) * HIDDEN + c8*8; \
  const u16* gA1 = (Abase) + (size_t)(m0 + wv*32 +  8 + rA) * HIDDEN + c8*8; \
  const u16* gA2 = (Abase) + (size_t)(m0 + wv*32 + 16 + rA) * HIDDEN + c8*8; \
  const u16* gA3 = (Abase) + (size_t)(m0 + wv*32 + 24 + rA) * HIDDEN + c8*8; \
  const u16* gB0 = (Wbase) + (size_t)(n0 + wv*16 +  0 + rA) * HIDDEN + c8*8; \
  const u16* gB1 = (Wbase) + (size_t)(n0 + wv*16 +  8 + rA) * HIDDEN + c8*8; \
  const int ldsA0 = (4*wv)*512 + lane*8; \
  const int ldsA1 = ldsA0 + 512; \
  const int ldsA2 = ldsA0 + 1024; \
  const int ldsA3 = ldsA0 + 1536; \
  const int ldsB0 = 16384 + (2*wv)*512 + lane*8; \
  const int ldsB1 = ldsB0 + 512; \
  const int s0q = ((quad    ) ^ (l16 & 7)) * 8; \
  const int s1q = ((quad + 4) ^ (l16 & 7)) * 8; \
  const int abase = (wm*128 + l16) * 64; \
  const int bbase = (wn*32  + l16) * 64; \
  f32x4 acc[8][2]; \
  _Pragma("unroll") \
  for (int i = 0; i < 8; i++) { acc[i][0] = (f32x4)0.0f; acc[i][1] = (f32x4)0.0f; } \
  STG(gA0, ldsA0); STG(gA1, ldsA1); STG(gB0, ldsB0); \
  STG(gA2, ldsA2); STG(gA3, ldsA3); STG(gB1, ldsB1); \
  STG(gA0 + 64, 24576 + ldsA0); STG(gA1 + 64, 24576 + ldsA1); STG(gB0 + 64, 24576 + ldsB0); \
  STG(gA2 + 64, 24576 + ldsA2); STG(gA3 + 64, 24576 + ldsA3); STG(gB1 + 64, 24576 + ldsB1); \
  asm volatile("s_waitcnt vmcnt(6)" ::: "memory"); \
  __builtin_amdgcn_s_barrier(); \
  for (int t = 0; t < NT32 - 2; ++t) GRP(t, 1, "vmcnt(6)"); \
  GRP(NT32 - 2, 0, "vmcnt(0)"); \
  GRP(NT32 - 1, 0, "vmcnt(63)");

// --- QKV: grid 768 (48 colTiles x 16 rowTiles), bf16 C.
// wix 0/1 (Q,K): RoPE fused into the epilogue (each 128-col tile == one head);
// Q additionally pre-scaled by 1/sqrt(128).  wix==2 (V): transposed Vt store.
__global__ __launch_bounds__(512, 2)
void gemm256_qkv(const u16* __restrict__ A,
                 const u16* __restrict__ W0, const u16* __restrict__ W1,
                 const u16* __restrict__ W2,
                 const float* __restrict__ bias0, const float* __restrict__ bias1,
                 const float* __restrict__ bias2,
                 u16* __restrict__ C0, u16* __restrict__ C1, u16* __restrict__ Vt)
{
  __shared__ __align__(16) u16 smem[73728];   // 144 KiB

  const int bid = blockIdx.x;
  const int sbid = (bid & 7) * 96 + (bid >> 3);   // 768 % 8 == 0, bijective
  const int colTile = sbid >> 4;        // 0..47
  const int rowTile = sbid & 15;        // 0..15
  const int wix = colTile >> 4;         // 0:Q 1:K 2:V
  const int n0  = (colTile & 15) * 128;
  const int m0  = rowTile * 256;

  const u16* Wp = (wix == 0) ? W0 : (wix == 1) ? W1 : W2;
  const float* bias = (wix == 0) ? bias0 : (wix == 1) ? bias1 : bias2;

  G256_SETUP(A, Wp)

  if (wix != 2) {
    // ---- fused-RoPE epilogue: acc+bias (xqscale for Q) -> LDS [256][128] bf16
    const float scale = (wix == 0) ? 0.08838834764831845f : 1.0f;
    u16* T = smem;
#pragma unroll
    for (int nt = 0; nt < 2; nt++) {
      const int nl = wn*32 + nt*16 + l16;
      const float bv = bias[n0 + nl];
#pragma unroll
      for (int mt = 0; mt < 8; mt++) {
        const int ml = wm*128 + mt*16 + quad*4;
#pragma unroll
        for (int r = 0; r < 4; r++)
          T[(ml + r)*128 + nl] = f2bf((acc[mt][nt][r] + bv) * scale);
      }
    }
    __syncthreads();

    // ---- rotate pairs (d, d+64); thread: row tid>>1, col-quarter tid&1
    u16* Cb = (wix == 0) ? C0 : C1;
    const int mr = tid >> 1, qd = tid & 1;
    const float s = (float)((m0 + mr) & 2047);
#pragma unroll
    for (int c8i = 0; c8i < 4; c8i++) {
      const int d0 = qd*32 + c8i*8;
      frag8 lo = *(const frag8*)&T[mr*128 + d0];
      frag8 hi = *(const frag8*)&T[mr*128 + 64 + d0];
      frag8 olo, ohi;
#pragma unroll
      for (int e = 0; e < 8; e++) {
        const float inv = __expf(-(float)(d0 + e) * (9.210340371976184f / 64.0f));
        float sn, c;
        __sincosf(s * inv, &sn, &c);
        const float x1 = bf2f((u16)lo[e]), x2 = bf2f((u16)hi[e]);
        olo[e] = (short)f2bf(x1 * c - x2 * sn);
        ohi[e] = (short)f2bf(x2 * c + x1 * sn);
      }
      *(frag8*)&Cb[(size_t)(m0 + mr) * HIDDEN + n0 + d0]      = olo;
      *(frag8*)&Cb[(size_t)(m0 + mr) * HIDDEN + n0 + 64 + d0] = ohi;
    }
  } else {
    u16* T = smem + wv * 2176;         // 16 x 136 u16 per wave
    const int b  = m0 >> 11;
    const int s0 = (m0 & 2047) + wm*128;
#pragma unroll
    for (int nt = 0; nt < 2; nt++) {
      const int nloc = n0 + wn*32 + nt*16;
      const float bv = bias[nloc + l16];
#pragma unroll
      for (int mt = 0; mt < 8; mt++)
#pragma unroll
        for (int r = 0; r < 4; r++)
          T[l16*136 + mt*16 + quad*4 + r] = f2bf(acc[mt][nt][r] + bv);
#pragma unroll
      for (int rr = 0; rr < 16; rr++) {
        const size_t vb = ((size_t)(b * HIDDEN + nloc + rr)) * SEQ + s0;
        Vt[vb + lane]      = T[rr*136 + lane];
        Vt[vb + 64 + lane] = T[rr*136 + 64 + lane];
      }
    }
  }
}

// --- out-proj: grid 256 (16 colTiles x 16 rowTiles), f32 C.
__global__ __launch_bounds__(512, 2)
void gemm256_o(const u16* __restrict__ A, const u16* __restrict__ W,
               const float* __restrict__ bias, float* __restrict__ C)
{
  __shared__ __align__(16) u16 smem[73728];   // 144 KiB

  const int bid = blockIdx.x;
  const int sbid = (bid & 7) * 32 + (bid >> 3);   // 256 % 8 == 0, bijective
  const int colTile = sbid >> 4;        // 0..15
  const int rowTile = sbid & 15;        // 0..15
  const int n0  = colTile * 128;
  const int m0  = rowTile * 256;

  G256_SETUP(A, W)

#pragma unroll
  for (int nt = 0; nt < 2; nt++) {
    const int n = n0 + wn*32 + nt*16 + l16;
    const float bv = bias[n];
#pragma unroll
    for (int mt = 0; mt < 8; mt++) {
      const int m = m0 + wm*128 + mt*16 + quad*4;
#pragma unroll
      for (int r = 0; r < 4; r++)
        C[(size_t)(m + r) * HIDDEN + n] = acc[mt][nt][r] + bv;
    }
  }
}

// ---------------------------------------------------------------------------
// RoPE in place on bf16 Q,K (slow path only; fast path fuses into GEMM).
// ---------------------------------------------------------------------------
__global__ void rope_kernel(u16* __restrict__ Q, u16* __restrict__ K)
{
  const int tid = blockIdx.x * 256 + threadIdx.x;   // 2^20 total
  const int t   = tid >> 19;           // 0:Q 1:K
  const int r   = tid & 524287;
  const int row = r >> 7;              // [0,4096)
  const int grp = r & 127;
  const int h   = grp >> 3, d0 = (grp & 7) * 8;
  u16* X = t ? K : Q;
  const float s = (float)(row & 2047);
  const float qscale = t ? 1.0f : 0.08838834764831845f;
  const size_t base = (size_t)row * HIDDEN + h * HDIM + d0;
  frag8 a = *(const frag8*)(X + base);
  frag8 b = *(const frag8*)(X + base + 64);
  frag8 oa, ob;
#pragma unroll
  for (int e = 0; e < 8; e++) {
    const float inv = __expf(-(float)(d0 + e) * (9.210340371976184f / 64.0f));
    float sn, c;
    __sincosf(s * inv, &sn, &c);
    const float x1 = bf2f((u16)a[e]), x2 = bf2f((u16)b[e]);
    oa[e] = (short)f2bf((x1 * c - x2 * sn) * qscale);
    ob[e] = (short)f2bf((x2 * c + x1 * sn) * qscale);
  }
  *(frag8*)(X + base)      = oa;
  *(frag8*)(X + base + 64) = ob;
}

// ---------------------------------------------------------------------------
// Flash attention (causal) — round-0 proven version (133.0 us, VGPR 80,
// no spill, 3 blocks/CU).  Q (pre-scaled+roped), K roped; Vt transposed.
// Grid 1024 = 32 qt x 32 bh.  Block 256 thr = 4 waves; Q-tile 64
// (16 q/wave), K-tile 64.  ktmax = qt+1; only kt==qt masks.
// ---------------------------------------------------------------------------
#define KS_STR 132
#define VS_STR 68
#define PS_STR 68
__global__ __launch_bounds__(256, 3)
void attn_kernel(const u16* Q, const u16* __restrict__ K,
                 const u16* __restrict__ Vt, u16* O)
{
  __shared__ __align__(16) u16 Ks[64 * KS_STR];     // [key][d]
  __shared__ __align__(16) u16 Vs[128 * VS_STR];    // [d][j]
  __shared__ __align__(16) u16 Ps[4 * 16 * PS_STR]; // per-wave [q][j]

  const int bx = blockIdx.x;
  const int g  = bx >> 5;                 // [0,32)
  const int bh = bx & 31;
  const int qt = (g & 1) ? (31 - (g >> 1)) : (g >> 1);   // zigzag balance
  const int b = bh >> 4, h = bh & 15;

  const int tid = threadIdx.x, lane = tid & 63, wv = tid >> 6;
  const int quad = lane >> 4, l16 = lane & 15;

  // Q A-fragments: lane holds Q[m = l16][d = ks*32 + quad*8 + j]
  frag8 qf[4];
  const size_t qbase = ((size_t)(b * SEQ) + qt*64 + wv*16) * HIDDEN + h * HDIM;
#pragma unroll
  for (int ks = 0; ks < 4; ks++)
    qf[ks] = *(const frag8*)(Q + qbase + (size_t)l16 * HIDDEN + ks*32 + quad*8);

  f32x4 Oacc[8];
#pragma unroll
  for (int dt = 0; dt < 8; dt++) Oacc[dt] = (f32x4)0.0f;
  float m_i[4], l_i[4];
#pragma unroll
  for (int r = 0; r < 4; r++) { m_i[r] = -1e30f; l_i[r] = 0.0f; }

  const int ktmax = qt + 1;
  const size_t krow0 = (size_t)(b * SEQ) * HIDDEN + h * HDIM;
  const size_t vrow0 = (size_t)(b * HIDDEN + h * HDIM) * SEQ;
  u16* Pw = Ps + wv * (16 * PS_STR);
  const int qmin = qt*64 + wv*16;

  for (int kt = 0; kt < ktmax; kt++) {
    // ---- stage K tile [64 keys][128 d]
#pragma unroll
    for (int it = 0; it < 4; it++) {
      const int G = it * 256 + tid;          // 0..1023
      const int key = G >> 4, gd = (G & 15) * 8;
      *(frag8*)&Ks[key * KS_STR + gd] =
        *(const frag8*)(K + krow0 + (size_t)(kt*64 + key) * HIDDEN + gd);
    }
    // ---- stage Vt tile [128 d][64 j]
#pragma unroll
    for (int it = 0; it < 4; it++) {
      const int G = it * 256 + tid;
      const int d = G >> 3, j8 = (G & 7) * 8;
      *(frag8*)&Vs[d * VS_STR + j8] =
        *(const frag8*)(Vt + vrow0 + (size_t)d * SEQ + kt*64 + j8);
    }
    __syncthreads();

    // ---- S = Q*K^T : 16 queries x 64 keys (Q pre-scaled)
    f32x4 st[4];
#pragma unroll
    for (int jt = 0; jt < 4; jt++) st[jt] = (f32x4)0.0f;

#pragma unroll
    for (int ks = 0; ks < 4; ks++) {
      frag8 kf[4];
#pragma unroll
      for (int jt = 0; jt < 4; jt++)
        kf[jt] = *(const frag8*)&Ks[(jt*16 + l16) * KS_STR + ks*32 + quad*8];
#pragma unroll
      for (int jt = 0; jt < 4; jt++)
        st[jt] = __builtin_amdgcn_mfma_f32_16x16x32_bf16(qf[ks], kf[jt], st[jt], 0, 0, 0);
    }

    // ---- causal mask on the diagonal tile only
    if (kt == qt) {
#pragma unroll
      for (int jt = 0; jt < 4; jt++) {
        const int jl = jt*16 + l16;          // key - kt*64
#pragma unroll
        for (int r = 0; r < 4; r++) {
          const int ml = wv*16 + quad*4 + r; // query - qt*64
          st[jt][r] = (jl <= ml) ? st[jt][r] : -1e30f;
        }
      }
    }

    // ---- online softmax per query row (r); reduce over l16 lanes
    float alpha[4];
#pragma unroll
    for (int r = 0; r < 4; r++) {
      float cm = st[0][r];
#pragma unroll
      for (int jt = 1; jt < 4; jt++) cm = fmaxf(cm, st[jt][r]);
      cm = fmaxf(cm, __shfl_xor(cm, 1, 64));
      cm = fmaxf(cm, __shfl_xor(cm, 2, 64));
      cm = fmaxf(cm, __shfl_xor(cm, 4, 64));
      cm = fmaxf(cm, __shfl_xor(cm, 8, 64));
      const float mnew = fmaxf(m_i[r], cm);
      alpha[r] = __expf(m_i[r] - mnew);
      m_i[r] = mnew;
    }

    // ---- p = exp(s - m); P -> LDS
    float csum[4];
#pragma unroll
    for (int r = 0; r < 4; r++) csum[r] = 0.0f;
#pragma unroll
    for (int jt = 0; jt < 4; jt++)
#pragma unroll
      for (int r = 0; r < 4; r++) {
        const float p = __expf(st[jt][r] - m_i[r]);
        csum[r] += p;
        Pw[(quad*4 + r) * PS_STR + jt*16 + l16] = f2bf(p);
      }
#pragma unroll
    for (int r = 0; r < 4; r++) {
      float cs = csum[r];
      cs += __shfl_xor(cs, 1, 64);
      cs += __shfl_xor(cs, 2, 64);
      cs += __shfl_xor(cs, 4, 64);
      cs += __shfl_xor(cs, 8, 64);
      l_i[r] = l_i[r] * alpha[r] + cs;
#pragma unroll
      for (int dt = 0; dt < 8; dt++) Oacc[dt][r] *= alpha[r];
    }

    // ---- O += P * V  (same-wave LDS RAW on Pw)
#pragma unroll
    for (int ks2 = 0; ks2 < 2; ks2++) {
      frag8 pf = *(const frag8*)&Pw[l16 * PS_STR + ks2*32 + quad*8];
#pragma unroll
      for (int dt = 0; dt < 8; dt++) {
        frag8 vf = *(const frag8*)&Vs[(dt*16 + l16) * VS_STR + ks2*32 + quad*8];
        Oacc[dt] = __builtin_amdgcn_mfma_f32_16x16x32_bf16(pf, vf, Oacc[dt], 0, 0, 0);
      }
    }
    __syncthreads();
  }

  // ---- finalize: /l_i, store merged [b*2048+m][h*128+d]
#pragma unroll
  for (int r = 0; r < 4; r++) {
    const float inv = 1.0f / l_i[r];
    const int m = qmin + quad*4 + r;
#pragma unroll
    for (int dt = 0; dt < 8; dt++) {
      const int d = dt*16 + l16;
      O[((size_t)(b * SEQ) + m) * HIDDEN + h * HDIM + d] = f2bf(Oacc[dt][r] * inv);
    }
  }
}

// ---------------------------------------------------------------------------
extern "C" void kernel_launch(void* const* d_in, const int* in_sizes, int n_in,
                              void* d_out, int out_size, void* d_ws, size_t ws_size,
                              hipStream_t stream)
{
  const float* X  = (const float*)d_in[0];
  const float* Wq = (const float*)d_in[1];
  const float* bq = (const float*)d_in[2];
  const float* Wk = (const float*)d_in[3];
  const float* bk = (const float*)d_in[4];
  const float* Wv = (const float*)d_in[5];
  const float* bv = (const float*)d_in[6];
  const float* Wo = (const float*)d_in[7];
  const float* bo = (const float*)d_in[8];
  float* out = (float*)d_out;

  u16* Kb = (u16*)d_out;
  u16* Xb = (u16*)d_out + (8u << 20);
  char* ws = (char*)d_ws;
  u16* Qb  = (u16*)ws;
  u16* Vtb = (u16*)(ws + (16u << 20));

  dim3 blk(256);
  const bool fast = ws_size >= (64u << 20);
  if (fast) {
    u16* Wqb = (u16*)(ws + (32u << 20));
    u16* Wkb = (u16*)(ws + (40u << 20));
    u16* Wvb = (u16*)(ws + (48u << 20));
    u16* Wob = (u16*)(ws + (56u << 20));
    cvt_all<<<12288, blk, 0, stream>>>(X, Wq, Wk, Wv, Wo, Xb, Wqb, Wkb, Wvb, Wob);
    gemm256_qkv<<<dim3(768), dim3(512), 0, stream>>>(
        Xb, Wqb, Wkb, Wvb, bq, bk, bv, Qb, Kb, Vtb);
    attn_kernel<<<1024, blk, 0, stream>>>(Qb, Kb, Vtb, Qb);
    gemm256_o<<<dim3(256), dim3(512), 0, stream>>>(Qb, Wob, bo, out);
  } else {
    cvt_all<<<4096, blk, 0, stream>>>(X, Wq, Wk, Wv, Wo, Xb, Xb, Xb, Xb, Xb);
    gemm_fused<0,3,1,0><<<dim3(48,32), blk, 0, stream>>>(
        Xb, Wq, Wk, Wv, bq, bk, bv, Qb, Kb, Vtb);
    rope_kernel<<<4096, blk, 0, stream>>>(Qb, Kb);
    attn_kernel<<<1024, blk, 0, stream>>>(Qb, Kb, Vtb, Qb);
    gemm_fused<0,1,0,1><<<dim3(16,32), blk, 0, stream>>>(
        Qb, Wo, Wo, Wo, bo, bo, bo, out, out, out);
  }
}

// Round 8
// 408.031 us; speedup vs baseline: 1.0889x; 1.0543x over previous
//
#include <hip/hip_runtime.h>

using u16 = unsigned short;
using u32 = unsigned int;

typedef __attribute__((ext_vector_type(4))) float f32x4;
typedef __attribute__((ext_vector_type(8))) short frag8;   // 8 x bf16 (4 VGPRs)

#define HIDDEN 2048
#define SEQ    2048
#define NHEADS 16
#define HDIM   128

__device__ __forceinline__ float bf2f(u16 u) {
  union { u32 i; float f; } c; c.i = ((u32)u) << 16; return c.f;
}
__device__ __forceinline__ u16 f2bf(float f) {   // RNE
  union { float f; u32 i; } c; c.f = f;
  u32 u = c.i + 0x7fffu + ((c.i >> 16) & 1u);
  return (u16)(u >> 16);
}

// ---------------------------------------------------------------------------
// Fused f32 -> bf16 convert for X + 4 weight matrices, ONE dispatch.
// ---------------------------------------------------------------------------
__global__ void cvt_all(const float* __restrict__ X,
                        const float* __restrict__ W0, const float* __restrict__ W1,
                        const float* __restrict__ W2, const float* __restrict__ W3,
                        u16* __restrict__ dX,
                        u16* __restrict__ dW0, u16* __restrict__ dW1,
                        u16* __restrict__ dW2, u16* __restrict__ dW3)
{
  const int bx = blockIdx.x;
  const float* s; u16* d; int g;
  if (bx < 4096) { s = X; d = dX; g = bx * 256 + threadIdx.x; }
  else {
    const int t = bx - 4096;
    const int w = t >> 11;               // 0..3
    s = (w == 0) ? W0 : (w == 1) ? W1 : (w == 2) ? W2 : W3;
    d = (w == 0) ? dW0 : (w == 1) ? dW1 : (w == 2) ? dW2 : dW3;
    g = (t & 2047) * 256 + threadIdx.x;
  }
  const float* p = s + (size_t)g * 8;
  f32x4 x0 = *(const f32x4*)p, x1 = *(const f32x4*)(p + 4);
  frag8 o;
#pragma unroll
  for (int e = 0; e < 4; e++) { o[e] = (short)f2bf(x0[e]); o[e+4] = (short)f2bf(x1[e]); }
  *(frag8*)(d + (size_t)g * 8) = o;
}

// ---------------------------------------------------------------------------
// OLD 128x128 fused NT GEMM (kept for the slow path).
// ---------------------------------------------------------------------------
template<int W_BF16, int NW, int VT, int C_F32>
__global__ __launch_bounds__(256, 4)
void gemm_fused(const u16* __restrict__ A,
                const void* __restrict__ W0, const void* __restrict__ W1,
                const void* __restrict__ W2,
                const float* __restrict__ bias0, const float* __restrict__ bias1,
                const float* __restrict__ bias2,
                void* __restrict__ C0, void* __restrict__ C1, void* __restrict__ C2)
{
  __shared__ __align__(16) u16 smem[8192];     // As [0,4096), Bs [4096,8192)
  u16* As = smem;
  u16* Bs = smem + 4096;

  const int tid  = threadIdx.x;
  const int lane = tid & 63;
  const int wv   = tid >> 6;
  const int quad = lane >> 4;
  const int l16  = lane & 15;
  const int wm = wv >> 1, wn = wv & 1;
  const int m0 = blockIdx.y * 128;
  const int wix = (NW == 1) ? 0 : (blockIdx.x >> 4);
  const int n0  = ((NW == 1) ? blockIdx.x : (blockIdx.x & 15)) * 128;

  const void* Wp = (wix == 0) ? W0 : (wix == 1) ? W1 : W2;
  const float* bias = (wix == 0) ? bias0 : (wix == 1) ? bias1 : bias2;
  void* Cp = (wix == 0) ? C0 : (wix == 1) ? C1 : C2;

  f32x4 acc[4][4];
#pragma unroll
  for (int i = 0; i < 4; i++)
#pragma unroll
    for (int j = 0; j < 4; j++) acc[i][j] = (f32x4)0.0f;

  const int g0 = tid, g1 = tid + 256;
  const int r0 = g0 >> 2, c0 = (g0 & 3) * 8;
  const int r1 = g1 >> 2, c1 = (g1 & 3) * 8;

  for (int k0 = 0; k0 < HIDDEN; k0 += 32) {
    __builtin_amdgcn_global_load_lds(
      (const __attribute__((address_space(1))) void*)(A + (size_t)(m0 + r0) * HIDDEN + k0 + c0),
      (__attribute__((address_space(3))) void*)(As + g0 * 8), 16, 0, 0);
    __builtin_amdgcn_global_load_lds(
      (const __attribute__((address_space(1))) void*)(A + (size_t)(m0 + r1) * HIDDEN + k0 + c1),
      (__attribute__((address_space(3))) void*)(As + g1 * 8), 16, 0, 0);
    if (W_BF16) {
      const u16* Wb = (const u16*)Wp;
      __builtin_amdgcn_global_load_lds(
        (const __attribute__((address_space(1))) void*)(Wb + (size_t)(n0 + r0) * HIDDEN + k0 + c0),
        (__attribute__((address_space(3))) void*)(Bs + g0 * 8), 16, 0, 0);
      __builtin_amdgcn_global_load_lds(
        (const __attribute__((address_space(1))) void*)(Wb + (size_t)(n0 + r1) * HIDDEN + k0 + c1),
        (__attribute__((address_space(3))) void*)(Bs + g1 * 8), 16, 0, 0);
    } else {
      const float* Wf = (const float*)Wp;
      const float* p0 = Wf + (size_t)(n0 + r0) * HIDDEN + k0 + c0;
      const float* p1 = Wf + (size_t)(n0 + r1) * HIDDEN + k0 + c1;
      f32x4 x0 = *(const f32x4*)p0, x1 = *(const f32x4*)(p0 + 4);
      f32x4 y0 = *(const f32x4*)p1, y1 = *(const f32x4*)(p1 + 4);
      frag8 b0v, b1v;
#pragma unroll
      for (int e = 0; e < 4; e++) {
        b0v[e]   = (short)f2bf(x0[e]); b0v[e+4] = (short)f2bf(x1[e]);
        b1v[e]   = (short)f2bf(y0[e]); b1v[e+4] = (short)f2bf(y1[e]);
      }
      *(frag8*)&Bs[g0 * 8] = b0v;
      *(frag8*)&Bs[g1 * 8] = b1v;
    }

    __builtin_amdgcn_s_waitcnt(0);   // drain DMA before barrier
    __syncthreads();

    frag8 af[4], bfr[4];
#pragma unroll
    for (int mt = 0; mt < 4; mt++)
      af[mt] = *(const frag8*)&As[(wm*64 + mt*16 + l16) * 32 + quad*8];
#pragma unroll
    for (int nt = 0; nt < 4; nt++)
      bfr[nt] = *(const frag8*)&Bs[(wn*64 + nt*16 + l16) * 32 + quad*8];
#pragma unroll
    for (int mt = 0; mt < 4; mt++)
#pragma unroll
      for (int nt = 0; nt < 4; nt++)
        acc[mt][nt] = __builtin_amdgcn_mfma_f32_16x16x32_bf16(af[mt], bfr[nt], acc[mt][nt], 0, 0, 0);

    __syncthreads();
  }

  if (VT && wix == 2) {
    u16* Cv = (u16*)Cp;
    u16* T = smem + wv * 1056;
#pragma unroll
    for (int nt = 0; nt < 4; nt++) {
      const int n  = n0 + wn*64 + nt*16 + l16;
      const float bv = bias[n];
#pragma unroll
      for (int mt = 0; mt < 4; mt++)
#pragma unroll
        for (int r = 0; r < 4; r++)
          T[l16 * 66 + mt*16 + quad*4 + r] = f2bf(acc[mt][nt][r] + bv);
#pragma unroll
      for (int rr = 0; rr < 16; rr++) {
        const int nn = n0 + wn*64 + nt*16 + rr;
        const int mm = m0 + wm*64 + lane;
        const int b = mm >> 11, s = mm & 2047;
        Cv[((size_t)(b * HIDDEN + nn)) * SEQ + s] = T[rr * 66 + lane];
      }
    }
  } else {
#pragma unroll
    for (int nt = 0; nt < 4; nt++) {
      const int n  = n0 + wn*64 + nt*16 + l16;
      const float bv = bias[n];
#pragma unroll
      for (int mt = 0; mt < 4; mt++) {
#pragma unroll
        for (int r = 0; r < 4; r++) {
          const int m = m0 + wm*64 + mt*16 + quad*4 + r;
          if (C_F32) ((float*)Cp)[(size_t)m * HIDDEN + n] = acc[mt][nt][r] + bv;
          else       ((u16*)Cp)[(size_t)m * HIDDEN + n]   = f2bf(acc[mt][nt][r] + bv);
        }
      }
    }
  }
}

// ---------------------------------------------------------------------------
// Deep-pipelined GEMM core: tile 256(M) x 128(N), BK=64, 512 thr = 8 waves.
// THIS ROUND: wave layout 4M x 2N (per-wave 64x64, M_rep=N_rep=4) — raises
// FLOP/LDS-byte 26 -> 32 (af reuse x4 instead of x2); 8 ds_read_b128 per
// 16 MFMA per phase.  3 LDS buffers, staged 2 K-tiles ahead, vmcnt(6).
// ---------------------------------------------------------------------------
#define NT32 32   // 2048 / 64 K-tiles

#define STG(gptr, lofs) __builtin_amdgcn_global_load_lds( \
    (const __attribute__((address_space(1))) void*)(gptr), \
    (__attribute__((address_space(3))) void*)(smem + (lofs)), 16, 0, 0)

#define GRP(t, DOSTAGE, WAITSTR) { \
  u16* As = smem + ((t) % 3) * 24576; \
  u16* Bs = As + 16384; \
  frag8 af[4], bfr[4]; \
  _Pragma("unroll") for (int mt = 0; mt < 4; mt++) \
    af[mt] = *(const frag8*)(As + abase + mt*1024 + s0q); \
  _Pragma("unroll") for (int nt = 0; nt < 4; nt++) \
    bfr[nt] = *(const frag8*)(Bs + bbase + nt*1024 + s0q); \
  if (DOSTAGE) { \
    const size_t ko = (size_t)((t)+2)*64; const int sb = (((t)+2)%3)*24576; \
    STG(gA0 + ko, sb + ldsA0); STG(gA1 + ko, sb + ldsA1); STG(gB0 + ko, sb + ldsB0); \
  } \
  __builtin_amdgcn_s_barrier(); \
  __builtin_amdgcn_s_setprio(1); \
  _Pragma("unroll") for (int mt = 0; mt < 4; mt++) \
    _Pragma("unroll") for (int nt = 0; nt < 4; nt++) \
      acc[mt][nt] = __builtin_amdgcn_mfma_f32_16x16x32_bf16(af[mt], bfr[nt], acc[mt][nt], 0,0,0); \
  __builtin_amdgcn_s_setprio(0); \
  __builtin_amdgcn_s_barrier(); \
  _Pragma("unroll") for (int mt = 0; mt < 4; mt++) \
    af[mt] = *(const frag8*)(As + abase + mt*1024 + s1q); \
  _Pragma("unroll") for (int nt = 0; nt < 4; nt++) \
    bfr[nt] = *(const frag8*)(Bs + bbase + nt*1024 + s1q); \
  if (DOSTAGE) { \
    const size_t ko = (size_t)((t)+2)*64; const int sb = (((t)+2)%3)*24576; \
    STG(gA2 + ko, sb + ldsA2); STG(gA3 + ko, sb + ldsA3); STG(gB1 + ko, sb + ldsB1); \
  } \
  __builtin_amdgcn_s_barrier(); \
  __builtin_amdgcn_s_setprio(1); \
  _Pragma("unroll") for (int mt = 0; mt < 4; mt++) \
    _Pragma("unroll") for (int nt = 0; nt < 4; nt++) \
      acc[mt][nt] = __builtin_amdgcn_mfma_f32_16x16x32_bf16(af[mt], bfr[nt], acc[mt][nt], 0,0,0); \
  __builtin_amdgcn_s_setprio(0); \
  asm volatile("s_waitcnt " WAITSTR ::: "memory"); \
  __builtin_amdgcn_s_barrier(); \
}

// common per-thread setup for the 256x128 core (defines all names GRP needs)
#define G256_SETUP(Abase, Wbase) \
  const int tid  = threadIdx.x; \
  const int lane = tid & 63; \
  const int wv   = tid >> 6; \
  const int quad = lane >> 4; \
  const int l16  = lane & 15; \
  const int wm = wv >> 1, wn = wv & 1; \
  const int c8 = (lane & 7) ^ (lane >> 3); \
  const int rA = lane >> 3; \
  const u16* gA0 = (Abase) + (size_t)(m0 + wv*32 +  0 + rA) * HIDDEN + c8*8; \
  const u16* gA1 = (Abase) + (size_t)(m0 + wv*32 +  8 + rA) * HIDDEN + c8*8; \
  const u16* gA2 = (Abase) + (size_t)(m0 + wv*32 + 16 + rA) * HIDDEN + c8*8; \
  const u16* gA3 = (Abase) + (size_t)(m0 + wv*32 + 24 + rA) * HIDDEN + c8*8; \
  const u16* gB0 = (Wbase) + (size_t)(n0 + wv*16 +  0 + rA) * HIDDEN + c8*8; \
  const u16* gB1 = (Wbase) + (size_t)(n0 + wv*16 +  8 + rA) * HIDDEN + c8*8; \
  const int ldsA0 = (4*wv)*512 + lane*8; \
  const int ldsA1 = ldsA0 + 512; \
  const int ldsA2 = ldsA0 + 1024; \
  const int ldsA3 = ldsA0 + 1536; \
  const int ldsB0 = 16384 + (2*wv)*512 + lane*8; \
  const int ldsB1 = ldsB0 + 512; \
  const int s0q = ((quad    ) ^ (l16 & 7)) * 8; \
  const int s1q = ((quad + 4) ^ (l16 & 7)) * 8; \
  const int abase = (wm*64 + l16) * 64; \
  const int bbase = (wn*64 + l16) * 64; \
  f32x4 acc[4][4]; \
  _Pragma("unroll") \
  for (int i = 0; i < 4; i++) \
    _Pragma("unroll") \
    for (int j = 0; j < 4; j++) acc[i][j] = (f32x4)0.0f; \
  STG(gA0, ldsA0); STG(gA1, ldsA1); STG(gB0, ldsB0); \
  STG(gA2, ldsA2); STG(gA3, ldsA3); STG(gB1, ldsB1); \
  STG(gA0 + 64, 24576 + ldsA0); STG(gA1 + 64, 24576 + ldsA1); STG(gB0 + 64, 24576 + ldsB0); \
  STG(gA2 + 64, 24576 + ldsA2); STG(gA3 + 64, 24576 + ldsA3); STG(gB1 + 64, 24576 + ldsB1); \
  asm volatile("s_waitcnt vmcnt(6)" ::: "memory"); \
  __builtin_amdgcn_s_barrier(); \
  for (int t = 0; t < NT32 - 2; ++t) GRP(t, 1, "vmcnt(6)"); \
  GRP(NT32 - 2, 0, "vmcnt(0)"); \
  GRP(NT32 - 1, 0, "vmcnt(63)");

// --- QKV: grid 768 (48 colTiles x 16 rowTiles), bf16 C.
// wix 0/1 (Q,K): RoPE fused into the epilogue (each 128-col tile == one head);
// Q additionally pre-scaled by 1/sqrt(128).  wix==2 (V): transposed Vt store.
__global__ __launch_bounds__(512, 2)
void gemm256_qkv(const u16* __restrict__ A,
                 const u16* __restrict__ W0, const u16* __restrict__ W1,
                 const u16* __restrict__ W2,
                 const float* __restrict__ bias0, const float* __restrict__ bias1,
                 const float* __restrict__ bias2,
                 u16* __restrict__ C0, u16* __restrict__ C1, u16* __restrict__ Vt)
{
  __shared__ __align__(16) u16 smem[73728];   // 144 KiB

  const int bid = blockIdx.x;
  const int sbid = (bid & 7) * 96 + (bid >> 3);   // 768 % 8 == 0, bijective
  const int colTile = sbid >> 4;        // 0..47
  const int rowTile = sbid & 15;        // 0..15
  const int wix = colTile >> 4;         // 0:Q 1:K 2:V
  const int n0  = (colTile & 15) * 128;
  const int m0  = rowTile * 256;

  const u16* Wp = (wix == 0) ? W0 : (wix == 1) ? W1 : W2;
  const float* bias = (wix == 0) ? bias0 : (wix == 1) ? bias1 : bias2;

  G256_SETUP(A, Wp)

  if (wix != 2) {
    // ---- fused-RoPE epilogue: acc+bias (xqscale for Q) -> LDS [256][128] bf16
    const float scale = (wix == 0) ? 0.08838834764831845f : 1.0f;
    u16* T = smem;
#pragma unroll
    for (int nt = 0; nt < 4; nt++) {
      const int nl = wn*64 + nt*16 + l16;
      const float bv = bias[n0 + nl];
#pragma unroll
      for (int mt = 0; mt < 4; mt++) {
        const int ml = wm*64 + mt*16 + quad*4;
#pragma unroll
        for (int r = 0; r < 4; r++)
          T[(ml + r)*128 + nl] = f2bf((acc[mt][nt][r] + bv) * scale);
      }
    }
    __syncthreads();

    // ---- rotate pairs (d, d+64); thread: row tid>>1, col-quarter tid&1
    u16* Cb = (wix == 0) ? C0 : C1;
    const int mr = tid >> 1, qd = tid & 1;
    const float s = (float)((m0 + mr) & 2047);
#pragma unroll
    for (int c8i = 0; c8i < 4; c8i++) {
      const int d0 = qd*32 + c8i*8;
      frag8 lo = *(const frag8*)&T[mr*128 + d0];
      frag8 hi = *(const frag8*)&T[mr*128 + 64 + d0];
      frag8 olo, ohi;
#pragma unroll
      for (int e = 0; e < 8; e++) {
        const float inv = __expf(-(float)(d0 + e) * (9.210340371976184f / 64.0f));
        float sn, c;
        __sincosf(s * inv, &sn, &c);
        const float x1 = bf2f((u16)lo[e]), x2 = bf2f((u16)hi[e]);
        olo[e] = (short)f2bf(x1 * c - x2 * sn);
        ohi[e] = (short)f2bf(x2 * c + x1 * sn);
      }
      *(frag8*)&Cb[(size_t)(m0 + mr) * HIDDEN + n0 + d0]      = olo;
      *(frag8*)&Cb[(size_t)(m0 + mr) * HIDDEN + n0 + 64 + d0] = ohi;
    }
  } else {
    // ---- V: transposed store.  Per wave: rows wm*64..+64, cols wn*64..+64.
    u16* T = smem + wv * 1152;         // 16 x 72 u16 per wave
    const int b  = m0 >> 11;
    const int s0 = (m0 & 2047) + wm*64;
#pragma unroll
    for (int nt = 0; nt < 4; nt++) {
      const int nloc = n0 + wn*64 + nt*16;
      const float bv = bias[nloc + l16];
#pragma unroll
      for (int mt = 0; mt < 4; mt++)
#pragma unroll
        for (int r = 0; r < 4; r++)
          T[l16*72 + mt*16 + quad*4 + r] = f2bf(acc[mt][nt][r] + bv);
#pragma unroll
      for (int rr = 0; rr < 16; rr++) {
        const size_t vb = ((size_t)(b * HIDDEN + nloc + rr)) * SEQ + s0;
        Vt[vb + lane] = T[rr*72 + lane];
      }
    }
  }
}

// --- out-proj: grid 256 (16 colTiles x 16 rowTiles), f32 C.
__global__ __launch_bounds__(512, 2)
void gemm256_o(const u16* __restrict__ A, const u16* __restrict__ W,
               const float* __restrict__ bias, float* __restrict__ C)
{
  __shared__ __align__(16) u16 smem[73728];   // 144 KiB

  const int bid = blockIdx.x;
  const int sbid = (bid & 7) * 32 + (bid >> 3);   // 256 % 8 == 0, bijective
  const int colTile = sbid >> 4;        // 0..15
  const int rowTile = sbid & 15;        // 0..15
  const int n0  = colTile * 128;
  const int m0  = rowTile * 256;

  G256_SETUP(A, W)

#pragma unroll
  for (int nt = 0; nt < 4; nt++) {
    const int n = n0 + wn*64 + nt*16 + l16;
    const float bv = bias[n];
#pragma unroll
    for (int mt = 0; mt < 4; mt++) {
      const int m = m0 + wm*64 + mt*16 + quad*4;
#pragma unroll
      for (int r = 0; r < 4; r++)
        C[(size_t)(m + r) * HIDDEN + n] = acc[mt][nt][r] + bv;
    }
  }
}

// ---------------------------------------------------------------------------
// RoPE in place on bf16 Q,K (slow path only; fast path fuses into GEMM).
// ---------------------------------------------------------------------------
__global__ void rope_kernel(u16* __restrict__ Q, u16* __restrict__ K)
{
  const int tid = blockIdx.x * 256 + threadIdx.x;   // 2^20 total
  const int t   = tid >> 19;           // 0:Q 1:K
  const int r   = tid & 524287;
  const int row = r >> 7;              // [0,4096)
  const int grp = r & 127;
  const int h   = grp >> 3, d0 = (grp & 7) * 8;
  u16* X = t ? K : Q;
  const float s = (float)(row & 2047);
  const float qscale = t ? 1.0f : 0.08838834764831845f;
  const size_t base = (size_t)row * HIDDEN + h * HDIM + d0;
  frag8 a = *(const frag8*)(X + base);
  frag8 b = *(const frag8*)(X + base + 64);
  frag8 oa, ob;
#pragma unroll
  for (int e = 0; e < 8; e++) {
    const float inv = __expf(-(float)(d0 + e) * (9.210340371976184f / 64.0f));
    float sn, c;
    __sincosf(s * inv, &sn, &c);
    const float x1 = bf2f((u16)a[e]), x2 = bf2f((u16)b[e]);
    oa[e] = (short)f2bf((x1 * c - x2 * sn) * qscale);
    ob[e] = (short)f2bf((x2 * c + x1 * sn) * qscale);
  }
  *(frag8*)(X + base)      = oa;
  *(frag8*)(X + base + 64) = ob;
}

// ---------------------------------------------------------------------------
// Flash attention (causal) — 64-q tile, DMA staging, 40 KiB LDS.
// Round-5 proven-correct code; launch bound fixed to (256,3) so the
// allocator does NOT drop to the 64-VGPR tier (round-5 spill bug).
// LDS 40960 B -> up to 4 blocks/CU if VGPR <= 128.
// LDS u16: Ks [0,8192)=[64][128] swz | Vs [8192,16384)=[128][64] swz |
//          Ps [16384,20480) per-wave [16][64] swz.
// ---------------------------------------------------------------------------
__global__ __launch_bounds__(256, 3)
void attn_kernel(const u16* Q, const u16* __restrict__ K,
                 const u16* __restrict__ Vt, u16* O)
{
  __shared__ __align__(16) u16 smem[20480];   // 40 KiB exactly

  const int bx = blockIdx.x;
  const int g  = bx >> 5;                 // [0,32)
  const int bh = bx & 31;
  const int qt = (g & 1) ? (31 - (g >> 1)) : (g >> 1);   // zigzag balance
  const int b = bh >> 4, h = bh & 15;

  const int tid = threadIdx.x, lane = tid & 63, wv = tid >> 6;
  const int quad = lane >> 4, l16 = lane & 15;
  const int l7 = l16 & 7;

  const size_t krow0 = (size_t)(b * SEQ) * HIDDEN + h * HDIM;
  const size_t vrow0 = (size_t)(b * HIDDEN + h * HDIM) * SEQ;

  // Q A-fragments: lane holds Q[m = l16][d = ks*32 + quad*8 + j]
  frag8 qf[4];
  const size_t qbase = ((size_t)(b * SEQ) + qt*64 + wv*16) * HIDDEN + h * HDIM;
#pragma unroll
  for (int ks = 0; ks < 4; ks++)
    qf[ks] = *(const frag8*)(Q + qbase + (size_t)l16 * HIDDEN + ks*32 + quad*8);

  // DMA staging addresses (round-4-proven geometry).
  const int kr4 = lane >> 4, kc = lane & 15;
  const int vr8 = lane >> 3;
  const u16* gK[4]; const u16* gV[4];
  int ldsK[4], ldsV[4];
#pragma unroll
  for (int it = 0; it < 4; it++) {
    const int kcs = kc ^ ((it*4 + kr4) & 7);
    gK[it] = K + krow0 + (size_t)(wv*16 + it*4 + kr4) * HIDDEN + kcs*8;
    ldsK[it] = (wv*16 + it*4)*128 + lane*8;
    const int vcs = (lane & 7) ^ vr8;
    gV[it] = Vt + vrow0 + (size_t)(wv*32 + it*8 + vr8) * SEQ + vcs*8;
    ldsV[it] = 8192 + (wv*32 + it*8)*64 + lane*8;
  }

  f32x4 Oacc[8];
#pragma unroll
  for (int dt = 0; dt < 8; dt++) Oacc[dt] = (f32x4)0.0f;
  float m_i[4], l_i[4];
#pragma unroll
  for (int r = 0; r < 4; r++) { m_i[r] = -1e30f; l_i[r] = 0.0f; }

  const int ktmax = qt + 1;
  u16* Pw = smem + 16384 + wv*1024;   // this wave's P: [16][64] swizzled

  for (int kt = 0; kt < ktmax; kt++) {
    // ---- stage K tile [64][128] + V tile [128][64] via DMA (serial)
#pragma unroll
    for (int it = 0; it < 4; it++) {
      __builtin_amdgcn_global_load_lds(
        (const __attribute__((address_space(1))) void*)(gK[it] + (size_t)kt*64*HIDDEN),
        (__attribute__((address_space(3))) void*)(smem + ldsK[it]), 16, 0, 0);
      __builtin_amdgcn_global_load_lds(
        (const __attribute__((address_space(1))) void*)(gV[it] + kt*64),
        (__attribute__((address_space(3))) void*)(smem + ldsV[it]), 16, 0, 0);
    }
    asm volatile("s_waitcnt vmcnt(0)" ::: "memory");
    __syncthreads();

    // ---- S = Q*K^T : 16 queries x 64 keys (Q pre-scaled), swizzled K reads
    f32x4 st[4];
#pragma unroll
    for (int jt = 0; jt < 4; jt++) st[jt] = (f32x4)0.0f;

    __builtin_amdgcn_s_setprio(1);
#pragma unroll
    for (int ks = 0; ks < 4; ks++) {
      frag8 kf[4];
#pragma unroll
      for (int jt = 0; jt < 4; jt++)
        kf[jt] = *(const frag8*)&smem[(jt*16 + l16)*128 + ((ks*4 + quad) ^ l7)*8];
#pragma unroll
      for (int jt = 0; jt < 4; jt++)
        st[jt] = __builtin_amdgcn_mfma_f32_16x16x32_bf16(qf[ks], kf[jt], st[jt], 0, 0, 0);
    }
    __builtin_amdgcn_s_setprio(0);

    // ---- causal mask on the diagonal tile only
    if (kt == qt) {
#pragma unroll
      for (int jt = 0; jt < 4; jt++) {
        const int jl = jt*16 + l16;
#pragma unroll
        for (int r = 0; r < 4; r++) {
          const int ml = wv*16 + quad*4 + r;
          st[jt][r] = (jl <= ml) ? st[jt][r] : -1e30f;
        }
      }
    }

    // ---- online softmax; T13 defer-max (THR=8)
    float alpha[4];
    int needresc = 0;
#pragma unroll
    for (int r = 0; r < 4; r++) {
      float cm = fmaxf(fmaxf(st[0][r], st[1][r]), fmaxf(st[2][r], st[3][r]));
      cm = fmaxf(cm, __shfl_xor(cm, 1, 64));
      cm = fmaxf(cm, __shfl_xor(cm, 2, 64));
      cm = fmaxf(cm, __shfl_xor(cm, 4, 64));
      cm = fmaxf(cm, __shfl_xor(cm, 8, 64));
      if (cm > m_i[r] + 8.0f) {
        alpha[r] = __expf(m_i[r] - cm);
        m_i[r] = cm;
        needresc = 1;
      } else {
        alpha[r] = 1.0f;
      }
    }

    // ---- p = exp(s - m); P -> LDS (swizzled: slot ^= row&7); row sums
    float csum[4];
#pragma unroll
    for (int r = 0; r < 4; r++) csum[r] = 0.0f;
#pragma unroll
    for (int jt = 0; jt < 4; jt++)
#pragma unroll
      for (int r = 0; r < 4; r++) {
        const float p = __expf(st[jt][r] - m_i[r]);
        csum[r] += p;
        const int prow = quad*4 + r;
        Pw[prow*64 + (((jt*2 + (l16 >> 3)) ^ (prow & 7)) << 3) + l7] = f2bf(p);
      }
#pragma unroll
    for (int r = 0; r < 4; r++) {
      float cs = csum[r];
      cs += __shfl_xor(cs, 1, 64);
      cs += __shfl_xor(cs, 2, 64);
      cs += __shfl_xor(cs, 4, 64);
      cs += __shfl_xor(cs, 8, 64);
      l_i[r] = l_i[r] * alpha[r] + cs;
    }
    if (__any(needresc)) {
#pragma unroll
      for (int r = 0; r < 4; r++)
#pragma unroll
        for (int dt = 0; dt < 8; dt++) Oacc[dt][r] *= alpha[r];
    }

    // ---- O += P * V  (same-wave LDS RAW on Pw; swizzled P and V reads)
    __builtin_amdgcn_s_setprio(1);
#pragma unroll
    for (int ks2 = 0; ks2 < 2; ks2++) {
      frag8 pf = *(const frag8*)&Pw[l16*64 + ((ks2*4 + quad) ^ l7)*8];
#pragma unroll
      for (int dt = 0; dt < 8; dt++) {
        frag8 vf = *(const frag8*)&smem[8192 + (dt*16 + l16)*64 + ((ks2*4 + quad) ^ l7)*8];
        Oacc[dt] = __builtin_amdgcn_mfma_f32_16x16x32_bf16(pf, vf, Oacc[dt], 0, 0, 0);
      }
    }
    __builtin_amdgcn_s_setprio(0);
    __syncthreads();   // protect Ks/Vs before next stage
  }

  // ---- finalize: /l_i, store merged [b*2048+m][h*128+d]
#pragma unroll
  for (int r = 0; r < 4; r++) {
    const float inv = 1.0f / l_i[r];
    const int m = qt*64 + wv*16 + quad*4 + r;
#pragma unroll
    for (int dt = 0; dt < 8; dt++) {
      const int d = dt*16 + l16;
      O[((size_t)(b * SEQ) + m) * HIDDEN + h * HDIM + d] = f2bf(Oacc[dt][r] * inv);
    }
  }
}

// ---------------------------------------------------------------------------
extern "C" void kernel_launch(void* const* d_in, const int* in_sizes, int n_in,
                              void* d_out, int out_size, void* d_ws, size_t ws_size,
                              hipStream_t stream)
{
  const float* X  = (const float*)d_in[0];
  const float* Wq = (const float*)d_in[1];
  const float* bq = (const float*)d_in[2];
  const float* Wk = (const float*)d_in[3];
  const float* bk = (const float*)d_in[4];
  const float* Wv = (const float*)d_in[5];
  const float* bv = (const float*)d_in[6];
  const float* Wo = (const float*)d_in[7];
  const float* bo = (const float*)d_in[8];
  float* out = (float*)d_out;

  u16* Kb = (u16*)d_out;
  u16* Xb = (u16*)d_out + (8u << 20);
  char* ws = (char*)d_ws;
  u16* Qb  = (u16*)ws;
  u16* Vtb = (u16*)(ws + (16u << 20));

  dim3 blk(256);
  const bool fast = ws_size >= (64u << 20);
  if (fast) {
    u16* Wqb = (u16*)(ws + (32u << 20));
    u16* Wkb = (u16*)(ws + (40u << 20));
    u16* Wvb = (u16*)(ws + (48u << 20));
    u16* Wob = (u16*)(ws + (56u << 20));
    cvt_all<<<12288, blk, 0, stream>>>(X, Wq, Wk, Wv, Wo, Xb, Wqb, Wkb, Wvb, Wob);
    gemm256_qkv<<<dim3(768), dim3(512), 0, stream>>>(
        Xb, Wqb, Wkb, Wvb, bq, bk, bv, Qb, Kb, Vtb);
    attn_kernel<<<1024, blk, 0, stream>>>(Qb, Kb, Vtb, Qb);
    gemm256_o<<<dim3(256), dim3(512), 0, stream>>>(Qb, Wob, bo, out);
  } else {
    cvt_all<<<4096, blk, 0, stream>>>(X, Wq, Wk, Wv, Wo, Xb, Xb, Xb, Xb, Xb);
    gemm_fused<0,3,1,0><<<dim3(48,32), blk, 0, stream>>>(
        Xb, Wq, Wk, Wv, bq, bk, bv, Qb, Kb, Vtb);
    rope_kernel<<<4096, blk, 0, stream>>>(Qb, Kb);
    attn_kernel<<<1024, blk, 0, stream>>>(Qb, Kb, Vtb, Qb);
    gemm_fused<0,1,0,1><<<dim3(16,32), blk, 0, stream>>>(
        Qb, Wo, Wo, Wo, bo, bo, bo, out, out, out);
  }
}

// Round 9
// 400.747 us; speedup vs baseline: 1.1087x; 1.0182x over previous
//
#include <hip/hip_runtime.h>

using u16 = unsigned short;
using u32 = unsigned int;

typedef __attribute__((ext_vector_type(4))) float f32x4;
typedef __attribute__((ext_vector_type(8))) short frag8;   // 8 x bf16 (4 VGPRs)

#define HIDDEN 2048
#define SEQ    2048
#define NHEADS 16
#define HDIM   128

__device__ __forceinline__ float bf2f(u16 u) {
  union { u32 i; float f; } c; c.i = ((u32)u) << 16; return c.f;
}
__device__ __forceinline__ u16 f2bf(float f) {   // RNE
  union { float f; u32 i; } c; c.f = f;
  u32 u = c.i + 0x7fffu + ((c.i >> 16) & 1u);
  return (u16)(u >> 16);
}

// ---------------------------------------------------------------------------
// Fused f32 -> bf16 convert for X + 4 weight matrices, ONE dispatch.
// ---------------------------------------------------------------------------
__global__ void cvt_all(const float* __restrict__ X,
                        const float* __restrict__ W0, const float* __restrict__ W1,
                        const float* __restrict__ W2, const float* __restrict__ W3,
                        u16* __restrict__ dX,
                        u16* __restrict__ dW0, u16* __restrict__ dW1,
                        u16* __restrict__ dW2, u16* __restrict__ dW3)
{
  const int bx = blockIdx.x;
  const float* s; u16* d; int g;
  if (bx < 4096) { s = X; d = dX; g = bx * 256 + threadIdx.x; }
  else {
    const int t = bx - 4096;
    const int w = t >> 11;               // 0..3
    s = (w == 0) ? W0 : (w == 1) ? W1 : (w == 2) ? W2 : W3;
    d = (w == 0) ? dW0 : (w == 1) ? dW1 : (w == 2) ? dW2 : dW3;
    g = (t & 2047) * 256 + threadIdx.x;
  }
  const float* p = s + (size_t)g * 8;
  f32x4 x0 = *(const f32x4*)p, x1 = *(const f32x4*)(p + 4);
  frag8 o;
#pragma unroll
  for (int e = 0; e < 4; e++) { o[e] = (short)f2bf(x0[e]); o[e+4] = (short)f2bf(x1[e]); }
  *(frag8*)(d + (size_t)g * 8) = o;
}

// ---------------------------------------------------------------------------
// OLD 128x128 fused NT GEMM (kept for the slow path).
// ---------------------------------------------------------------------------
template<int W_BF16, int NW, int VT, int C_F32>
__global__ __launch_bounds__(256, 4)
void gemm_fused(const u16* __restrict__ A,
                const void* __restrict__ W0, const void* __restrict__ W1,
                const void* __restrict__ W2,
                const float* __restrict__ bias0, const float* __restrict__ bias1,
                const float* __restrict__ bias2,
                void* __restrict__ C0, void* __restrict__ C1, void* __restrict__ C2)
{
  __shared__ __align__(16) u16 smem[8192];     // As [0,4096), Bs [4096,8192)
  u16* As = smem;
  u16* Bs = smem + 4096;

  const int tid  = threadIdx.x;
  const int lane = tid & 63;
  const int wv   = tid >> 6;
  const int quad = lane >> 4;
  const int l16  = lane & 15;
  const int wm = wv >> 1, wn = wv & 1;
  const int m0 = blockIdx.y * 128;
  const int wix = (NW == 1) ? 0 : (blockIdx.x >> 4);
  const int n0  = ((NW == 1) ? blockIdx.x : (blockIdx.x & 15)) * 128;

  const void* Wp = (wix == 0) ? W0 : (wix == 1) ? W1 : W2;
  const float* bias = (wix == 0) ? bias0 : (wix == 1) ? bias1 : bias2;
  void* Cp = (wix == 0) ? C0 : (wix == 1) ? C1 : C2;

  f32x4 acc[4][4];
#pragma unroll
  for (int i = 0; i < 4; i++)
#pragma unroll
    for (int j = 0; j < 4; j++) acc[i][j] = (f32x4)0.0f;

  const int g0 = tid, g1 = tid + 256;
  const int r0 = g0 >> 2, c0 = (g0 & 3) * 8;
  const int r1 = g1 >> 2, c1 = (g1 & 3) * 8;

  for (int k0 = 0; k0 < HIDDEN; k0 += 32) {
    __builtin_amdgcn_global_load_lds(
      (const __attribute__((address_space(1))) void*)(A + (size_t)(m0 + r0) * HIDDEN + k0 + c0),
      (__attribute__((address_space(3))) void*)(As + g0 * 8), 16, 0, 0);
    __builtin_amdgcn_global_load_lds(
      (const __attribute__((address_space(1))) void*)(A + (size_t)(m0 + r1) * HIDDEN + k0 + c1),
      (__attribute__((address_space(3))) void*)(As + g1 * 8), 16, 0, 0);
    if (W_BF16) {
      const u16* Wb = (const u16*)Wp;
      __builtin_amdgcn_global_load_lds(
        (const __attribute__((address_space(1))) void*)(Wb + (size_t)(n0 + r0) * HIDDEN + k0 + c0),
        (__attribute__((address_space(3))) void*)(Bs + g0 * 8), 16, 0, 0);
      __builtin_amdgcn_global_load_lds(
        (const __attribute__((address_space(1))) void*)(Wb + (size_t)(n0 + r1) * HIDDEN + k0 + c1),
        (__attribute__((address_space(3))) void*)(Bs + g1 * 8), 16, 0, 0);
    } else {
      const float* Wf = (const float*)Wp;
      const float* p0 = Wf + (size_t)(n0 + r0) * HIDDEN + k0 + c0;
      const float* p1 = Wf + (size_t)(n0 + r1) * HIDDEN + k0 + c1;
      f32x4 x0 = *(const f32x4*)p0, x1 = *(const f32x4*)(p0 + 4);
      f32x4 y0 = *(const f32x4*)p1, y1 = *(const f32x4*)(p1 + 4);
      frag8 b0v, b1v;
#pragma unroll
      for (int e = 0; e < 4; e++) {
        b0v[e]   = (short)f2bf(x0[e]); b0v[e+4] = (short)f2bf(x1[e]);
        b1v[e]   = (short)f2bf(y0[e]); b1v[e+4] = (short)f2bf(y1[e]);
      }
      *(frag8*)&Bs[g0 * 8] = b0v;
      *(frag8*)&Bs[g1 * 8] = b1v;
    }

    __builtin_amdgcn_s_waitcnt(0);   // drain DMA before barrier
    __syncthreads();

    frag8 af[4], bfr[4];
#pragma unroll
    for (int mt = 0; mt < 4; mt++)
      af[mt] = *(const frag8*)&As[(wm*64 + mt*16 + l16) * 32 + quad*8];
#pragma unroll
    for (int nt = 0; nt < 4; nt++)
      bfr[nt] = *(const frag8*)&Bs[(wn*64 + nt*16 + l16) * 32 + quad*8];
#pragma unroll
    for (int mt = 0; mt < 4; mt++)
#pragma unroll
      for (int nt = 0; nt < 4; nt++)
        acc[mt][nt] = __builtin_amdgcn_mfma_f32_16x16x32_bf16(af[mt], bfr[nt], acc[mt][nt], 0, 0, 0);

    __syncthreads();
  }

  if (VT && wix == 2) {
    u16* Cv = (u16*)Cp;
    u16* T = smem + wv * 1056;
#pragma unroll
    for (int nt = 0; nt < 4; nt++) {
      const int n  = n0 + wn*64 + nt*16 + l16;
      const float bv = bias[n];
#pragma unroll
      for (int mt = 0; mt < 4; mt++)
#pragma unroll
        for (int r = 0; r < 4; r++)
          T[l16 * 66 + mt*16 + quad*4 + r] = f2bf(acc[mt][nt][r] + bv);
#pragma unroll
      for (int rr = 0; rr < 16; rr++) {
        const int nn = n0 + wn*64 + nt*16 + rr;
        const int mm = m0 + wm*64 + lane;
        const int b = mm >> 11, s = mm & 2047;
        Cv[((size_t)(b * HIDDEN + nn)) * SEQ + s] = T[rr * 66 + lane];
      }
    }
  } else {
#pragma unroll
    for (int nt = 0; nt < 4; nt++) {
      const int n  = n0 + wn*64 + nt*16 + l16;
      const float bv = bias[n];
#pragma unroll
      for (int mt = 0; mt < 4; mt++) {
#pragma unroll
        for (int r = 0; r < 4; r++) {
          const int m = m0 + wm*64 + mt*16 + quad*4 + r;
          if (C_F32) ((float*)Cp)[(size_t)m * HIDDEN + n] = acc[mt][nt][r] + bv;
          else       ((u16*)Cp)[(size_t)m * HIDDEN + n]   = f2bf(acc[mt][nt][r] + bv);
        }
      }
    }
  }
}

// ---------------------------------------------------------------------------
// Deep-pipelined GEMM core: tile 256(M) x 128(N), BK=64, 512 thr = 8 waves
// (4M x 2N, per-wave 64x64).  THIS ROUND: ONE barrier per K-tile.
// GRP(t) = { issue 6 stage DMAs (tile t+2) ; read ALL 16 fragments of buf t ;
//            lgkmcnt(0)+vmcnt(6) ; s_barrier ; 32 MFMA }.
// Safety: buf-t reads covered by GRP(t-1)'s vmcnt+barrier; pre-barrier
// lgkmcnt(0) drains every wave's reads of the buffer GRP(t+1) will overwrite.
// ---------------------------------------------------------------------------
#define NT32 32   // 2048 / 64 K-tiles

#define STG(gptr, lofs) __builtin_amdgcn_global_load_lds( \
    (const __attribute__((address_space(1))) void*)(gptr), \
    (__attribute__((address_space(3))) void*)(smem + (lofs)), 16, 0, 0)

#define GRP(t, DOSTAGE, WAITSTR) { \
  u16* As = smem + ((t) % 3) * 24576; \
  u16* Bs = As + 16384; \
  if (DOSTAGE) { \
    const size_t ko = (size_t)((t)+2)*64; const int sb = (((t)+2)%3)*24576; \
    STG(gA0 + ko, sb + ldsA0); STG(gA1 + ko, sb + ldsA1); STG(gB0 + ko, sb + ldsB0); \
    STG(gA2 + ko, sb + ldsA2); STG(gA3 + ko, sb + ldsA3); STG(gB1 + ko, sb + ldsB1); \
  } \
  frag8 af0[4], bf0[4], af1[4], bf1[4]; \
  _Pragma("unroll") for (int mt = 0; mt < 4; mt++) \
    af0[mt] = *(const frag8*)(As + abase + mt*1024 + s0q); \
  _Pragma("unroll") for (int nt = 0; nt < 4; nt++) \
    bf0[nt] = *(const frag8*)(Bs + bbase + nt*1024 + s0q); \
  _Pragma("unroll") for (int mt = 0; mt < 4; mt++) \
    af1[mt] = *(const frag8*)(As + abase + mt*1024 + s1q); \
  _Pragma("unroll") for (int nt = 0; nt < 4; nt++) \
    bf1[nt] = *(const frag8*)(Bs + bbase + nt*1024 + s1q); \
  asm volatile("s_waitcnt lgkmcnt(0) " WAITSTR ::: "memory"); \
  __builtin_amdgcn_s_barrier(); \
  __builtin_amdgcn_s_setprio(1); \
  _Pragma("unroll") for (int mt = 0; mt < 4; mt++) \
    _Pragma("unroll") for (int nt = 0; nt < 4; nt++) \
      acc[mt][nt] = __builtin_amdgcn_mfma_f32_16x16x32_bf16(af0[mt], bf0[nt], acc[mt][nt], 0,0,0); \
  _Pragma("unroll") for (int mt = 0; mt < 4; mt++) \
    _Pragma("unroll") for (int nt = 0; nt < 4; nt++) \
      acc[mt][nt] = __builtin_amdgcn_mfma_f32_16x16x32_bf16(af1[mt], bf1[nt], acc[mt][nt], 0,0,0); \
  __builtin_amdgcn_s_setprio(0); \
}

// common per-thread setup for the 256x128 core (defines all names GRP needs)
#define G256_SETUP(Abase, Wbase) \
  const int tid  = threadIdx.x; \
  const int lane = tid & 63; \
  const int wv   = tid >> 6; \
  const int quad = lane >> 4; \
  const int l16  = lane & 15; \
  const int wm = wv >> 1, wn = wv & 1; \
  const int c8 = (lane & 7) ^ (lane >> 3); \
  const int rA = lane >> 3; \
  const u16* gA0 = (Abase) + (size_t)(m0 + wv*32 +  0 + rA) * HIDDEN + c8*8; \
  const u16* gA1 = (Abase) + (size_t)(m0 + wv*32 +  8 + rA) * HIDDEN + c8*8; \
  const u16* gA2 = (Abase) + (size_t)(m0 + wv*32 + 16 + rA) * HIDDEN + c8*8; \
  const u16* gA3 = (Abase) + (size_t)(m0 + wv*32 + 24 + rA) * HIDDEN + c8*8; \
  const u16* gB0 = (Wbase) + (size_t)(n0 + wv*16 +  0 + rA) * HIDDEN + c8*8; \
  const u16* gB1 = (Wbase) + (size_t)(n0 + wv*16 +  8 + rA) * HIDDEN + c8*8; \
  const int ldsA0 = (4*wv)*512 + lane*8; \
  const int ldsA1 = ldsA0 + 512; \
  const int ldsA2 = ldsA0 + 1024; \
  const int ldsA3 = ldsA0 + 1536; \
  const int ldsB0 = 16384 + (2*wv)*512 + lane*8; \
  const int ldsB1 = ldsB0 + 512; \
  const int s0q = ((quad    ) ^ (l16 & 7)) * 8; \
  const int s1q = ((quad + 4) ^ (l16 & 7)) * 8; \
  const int abase = (wm*64 + l16) * 64; \
  const int bbase = (wn*64 + l16) * 64; \
  f32x4 acc[4][4]; \
  _Pragma("unroll") \
  for (int i = 0; i < 4; i++) \
    _Pragma("unroll") \
    for (int j = 0; j < 4; j++) acc[i][j] = (f32x4)0.0f; \
  STG(gA0, ldsA0); STG(gA1, ldsA1); STG(gB0, ldsB0); \
  STG(gA2, ldsA2); STG(gA3, ldsA3); STG(gB1, ldsB1); \
  STG(gA0 + 64, 24576 + ldsA0); STG(gA1 + 64, 24576 + ldsA1); STG(gB0 + 64, 24576 + ldsB0); \
  STG(gA2 + 64, 24576 + ldsA2); STG(gA3 + 64, 24576 + ldsA3); STG(gB1 + 64, 24576 + ldsB1); \
  asm volatile("s_waitcnt vmcnt(6)" ::: "memory"); \
  __builtin_amdgcn_s_barrier(); \
  for (int t = 0; t < NT32 - 2; ++t) GRP(t, 1, "vmcnt(6)"); \
  GRP(NT32 - 2, 0, "vmcnt(0)"); \
  GRP(NT32 - 1, 0, "vmcnt(63)"); \
  __syncthreads();

// --- QKV: grid 768 (48 colTiles x 16 rowTiles), bf16 C.
// wix 0/1 (Q,K): RoPE fused into the epilogue (each 128-col tile == one head);
// Q additionally pre-scaled by 1/sqrt(128).  wix==2 (V): transposed Vt store.
__global__ __launch_bounds__(512, 1)
void gemm256_qkv(const u16* __restrict__ A,
                 const u16* __restrict__ W0, const u16* __restrict__ W1,
                 const u16* __restrict__ W2,
                 const float* __restrict__ bias0, const float* __restrict__ bias1,
                 const float* __restrict__ bias2,
                 u16* __restrict__ C0, u16* __restrict__ C1, u16* __restrict__ Vt)
{
  __shared__ __align__(16) u16 smem[73728];   // 144 KiB

  const int bid = blockIdx.x;
  const int sbid = (bid & 7) * 96 + (bid >> 3);   // 768 % 8 == 0, bijective
  const int colTile = sbid >> 4;        // 0..47
  const int rowTile = sbid & 15;        // 0..15
  const int wix = colTile >> 4;         // 0:Q 1:K 2:V
  const int n0  = (colTile & 15) * 128;
  const int m0  = rowTile * 256;

  const u16* Wp = (wix == 0) ? W0 : (wix == 1) ? W1 : W2;
  const float* bias = (wix == 0) ? bias0 : (wix == 1) ? bias1 : bias2;

  G256_SETUP(A, Wp)

  if (wix != 2) {
    // ---- fused-RoPE epilogue: acc+bias (xqscale for Q) -> LDS [256][128] bf16
    const float scale = (wix == 0) ? 0.08838834764831845f : 1.0f;
    u16* T = smem;
#pragma unroll
    for (int nt = 0; nt < 4; nt++) {
      const int nl = wn*64 + nt*16 + l16;
      const float bv = bias[n0 + nl];
#pragma unroll
      for (int mt = 0; mt < 4; mt++) {
        const int ml = wm*64 + mt*16 + quad*4;
#pragma unroll
        for (int r = 0; r < 4; r++)
          T[(ml + r)*128 + nl] = f2bf((acc[mt][nt][r] + bv) * scale);
      }
    }
    __syncthreads();

    // ---- rotate pairs (d, d+64); thread: row tid>>1, col-quarter tid&1
    u16* Cb = (wix == 0) ? C0 : C1;
    const int mr = tid >> 1, qd = tid & 1;
    const float s = (float)((m0 + mr) & 2047);
#pragma unroll
    for (int c8i = 0; c8i < 4; c8i++) {
      const int d0 = qd*32 + c8i*8;
      frag8 lo = *(const frag8*)&T[mr*128 + d0];
      frag8 hi = *(const frag8*)&T[mr*128 + 64 + d0];
      frag8 olo, ohi;
#pragma unroll
      for (int e = 0; e < 8; e++) {
        const float inv = __expf(-(float)(d0 + e) * (9.210340371976184f / 64.0f));
        float sn, c;
        __sincosf(s * inv, &sn, &c);
        const float x1 = bf2f((u16)lo[e]), x2 = bf2f((u16)hi[e]);
        olo[e] = (short)f2bf(x1 * c - x2 * sn);
        ohi[e] = (short)f2bf(x2 * c + x1 * sn);
      }
      *(frag8*)&Cb[(size_t)(m0 + mr) * HIDDEN + n0 + d0]      = olo;
      *(frag8*)&Cb[(size_t)(m0 + mr) * HIDDEN + n0 + 64 + d0] = ohi;
    }
  } else {
    // ---- V: transposed store.  Per wave: rows wm*64..+64, cols wn*64..+64.
    u16* T = smem + wv * 1152;         // 16 x 72 u16 per wave
    const int b  = m0 >> 11;
    const int s0 = (m0 & 2047) + wm*64;
#pragma unroll
    for (int nt = 0; nt < 4; nt++) {
      const int nloc = n0 + wn*64 + nt*16;
      const float bv = bias[nloc + l16];
#pragma unroll
      for (int mt = 0; mt < 4; mt++)
#pragma unroll
        for (int r = 0; r < 4; r++)
          T[l16*72 + mt*16 + quad*4 + r] = f2bf(acc[mt][nt][r] + bv);
#pragma unroll
      for (int rr = 0; rr < 16; rr++) {
        const size_t vb = ((size_t)(b * HIDDEN + nloc + rr)) * SEQ + s0;
        Vt[vb + lane] = T[rr*72 + lane];
      }
    }
  }
}

// --- out-proj: grid 256 (16 colTiles x 16 rowTiles), f32 C.
__global__ __launch_bounds__(512, 1)
void gemm256_o(const u16* __restrict__ A, const u16* __restrict__ W,
               const float* __restrict__ bias, float* __restrict__ C)
{
  __shared__ __align__(16) u16 smem[73728];   // 144 KiB

  const int bid = blockIdx.x;
  const int sbid = (bid & 7) * 32 + (bid >> 3);   // 256 % 8 == 0, bijective
  const int colTile = sbid >> 4;        // 0..15
  const int rowTile = sbid & 15;        // 0..15
  const int n0  = colTile * 128;
  const int m0  = rowTile * 256;

  G256_SETUP(A, W)

#pragma unroll
  for (int nt = 0; nt < 4; nt++) {
    const int n = n0 + wn*64 + nt*16 + l16;
    const float bv = bias[n];
#pragma unroll
    for (int mt = 0; mt < 4; mt++) {
      const int m = m0 + wm*64 + mt*16 + quad*4;
#pragma unroll
      for (int r = 0; r < 4; r++)
        C[(size_t)(m + r) * HIDDEN + n] = acc[mt][nt][r] + bv;
    }
  }
}

// ---------------------------------------------------------------------------
// RoPE in place on bf16 Q,K (slow path only; fast path fuses into GEMM).
// ---------------------------------------------------------------------------
__global__ void rope_kernel(u16* __restrict__ Q, u16* __restrict__ K)
{
  const int tid = blockIdx.x * 256 + threadIdx.x;   // 2^20 total
  const int t   = tid >> 19;           // 0:Q 1:K
  const int r   = tid & 524287;
  const int row = r >> 7;              // [0,4096)
  const int grp = r & 127;
  const int h   = grp >> 3, d0 = (grp & 7) * 8;
  u16* X = t ? K : Q;
  const float s = (float)(row & 2047);
  const float qscale = t ? 1.0f : 0.08838834764831845f;
  const size_t base = (size_t)row * HIDDEN + h * HDIM + d0;
  frag8 a = *(const frag8*)(X + base);
  frag8 b = *(const frag8*)(X + base + 64);
  frag8 oa, ob;
#pragma unroll
  for (int e = 0; e < 8; e++) {
    const float inv = __expf(-(float)(d0 + e) * (9.210340371976184f / 64.0f));
    float sn, c;
    __sincosf(s * inv, &sn, &c);
    const float x1 = bf2f((u16)a[e]), x2 = bf2f((u16)b[e]);
    oa[e] = (short)f2bf((x1 * c - x2 * sn) * qscale);
    ob[e] = (short)f2bf((x2 * c + x1 * sn) * qscale);
  }
  *(frag8*)(X + base)      = oa;
  *(frag8*)(X + base + 64) = ob;
}

// ---------------------------------------------------------------------------
// Flash attention (causal) — 64-q tile, DMA staging, 40 KiB LDS, (256,3).
// Unchanged from round 7 (steady-state < 128 us, no spill).
// ---------------------------------------------------------------------------
__global__ __launch_bounds__(256, 3)
void attn_kernel(const u16* Q, const u16* __restrict__ K,
                 const u16* __restrict__ Vt, u16* O)
{
  __shared__ __align__(16) u16 smem[20480];   // 40 KiB exactly

  const int bx = blockIdx.x;
  const int g  = bx >> 5;                 // [0,32)
  const int bh = bx & 31;
  const int qt = (g & 1) ? (31 - (g >> 1)) : (g >> 1);   // zigzag balance
  const int b = bh >> 4, h = bh & 15;

  const int tid = threadIdx.x, lane = tid & 63, wv = tid >> 6;
  const int quad = lane >> 4, l16 = lane & 15;
  const int l7 = l16 & 7;

  const size_t krow0 = (size_t)(b * SEQ) * HIDDEN + h * HDIM;
  const size_t vrow0 = (size_t)(b * HIDDEN + h * HDIM) * SEQ;

  // Q A-fragments: lane holds Q[m = l16][d = ks*32 + quad*8 + j]
  frag8 qf[4];
  const size_t qbase = ((size_t)(b * SEQ) + qt*64 + wv*16) * HIDDEN + h * HDIM;
#pragma unroll
  for (int ks = 0; ks < 4; ks++)
    qf[ks] = *(const frag8*)(Q + qbase + (size_t)l16 * HIDDEN + ks*32 + quad*8);

  // DMA staging addresses (round-4-proven geometry).
  const int kr4 = lane >> 4, kc = lane & 15;
  const int vr8 = lane >> 3;
  const u16* gK[4]; const u16* gV[4];
  int ldsK[4], ldsV[4];
#pragma unroll
  for (int it = 0; it < 4; it++) {
    const int kcs = kc ^ ((it*4 + kr4) & 7);
    gK[it] = K + krow0 + (size_t)(wv*16 + it*4 + kr4) * HIDDEN + kcs*8;
    ldsK[it] = (wv*16 + it*4)*128 + lane*8;
    const int vcs = (lane & 7) ^ vr8;
    gV[it] = Vt + vrow0 + (size_t)(wv*32 + it*8 + vr8) * SEQ + vcs*8;
    ldsV[it] = 8192 + (wv*32 + it*8)*64 + lane*8;
  }

  f32x4 Oacc[8];
#pragma unroll
  for (int dt = 0; dt < 8; dt++) Oacc[dt] = (f32x4)0.0f;
  float m_i[4], l_i[4];
#pragma unroll
  for (int r = 0; r < 4; r++) { m_i[r] = -1e30f; l_i[r] = 0.0f; }

  const int ktmax = qt + 1;
  u16* Pw = smem + 16384 + wv*1024;   // this wave's P: [16][64] swizzled

  for (int kt = 0; kt < ktmax; kt++) {
    // ---- stage K tile [64][128] + V tile [128][64] via DMA (serial)
#pragma unroll
    for (int it = 0; it < 4; it++) {
      __builtin_amdgcn_global_load_lds(
        (const __attribute__((address_space(1))) void*)(gK[it] + (size_t)kt*64*HIDDEN),
        (__attribute__((address_space(3))) void*)(smem + ldsK[it]), 16, 0, 0);
      __builtin_amdgcn_global_load_lds(
        (const __attribute__((address_space(1))) void*)(gV[it] + kt*64),
        (__attribute__((address_space(3))) void*)(smem + ldsV[it]), 16, 0, 0);
    }
    asm volatile("s_waitcnt vmcnt(0)" ::: "memory");
    __syncthreads();

    // ---- S = Q*K^T : 16 queries x 64 keys (Q pre-scaled), swizzled K reads
    f32x4 st[4];
#pragma unroll
    for (int jt = 0; jt < 4; jt++) st[jt] = (f32x4)0.0f;

    __builtin_amdgcn_s_setprio(1);
#pragma unroll
    for (int ks = 0; ks < 4; ks++) {
      frag8 kf[4];
#pragma unroll
      for (int jt = 0; jt < 4; jt++)
        kf[jt] = *(const frag8*)&smem[(jt*16 + l16)*128 + ((ks*4 + quad) ^ l7)*8];
#pragma unroll
      for (int jt = 0; jt < 4; jt++)
        st[jt] = __builtin_amdgcn_mfma_f32_16x16x32_bf16(qf[ks], kf[jt], st[jt], 0, 0, 0);
    }
    __builtin_amdgcn_s_setprio(0);

    // ---- causal mask on the diagonal tile only
    if (kt == qt) {
#pragma unroll
      for (int jt = 0; jt < 4; jt++) {
        const int jl = jt*16 + l16;
#pragma unroll
        for (int r = 0; r < 4; r++) {
          const int ml = wv*16 + quad*4 + r;
          st[jt][r] = (jl <= ml) ? st[jt][r] : -1e30f;
        }
      }
    }

    // ---- online softmax; T13 defer-max (THR=8)
    float alpha[4];
    int needresc = 0;
#pragma unroll
    for (int r = 0; r < 4; r++) {
      float cm = fmaxf(fmaxf(st[0][r], st[1][r]), fmaxf(st[2][r], st[3][r]));
      cm = fmaxf(cm, __shfl_xor(cm, 1, 64));
      cm = fmaxf(cm, __shfl_xor(cm, 2, 64));
      cm = fmaxf(cm, __shfl_xor(cm, 4, 64));
      cm = fmaxf(cm, __shfl_xor(cm, 8, 64));
      if (cm > m_i[r] + 8.0f) {
        alpha[r] = __expf(m_i[r] - cm);
        m_i[r] = cm;
        needresc = 1;
      } else {
        alpha[r] = 1.0f;
      }
    }

    // ---- p = exp(s - m); P -> LDS (swizzled: slot ^= row&7); row sums
    float csum[4];
#pragma unroll
    for (int r = 0; r < 4; r++) csum[r] = 0.0f;
#pragma unroll
    for (int jt = 0; jt < 4; jt++)
#pragma unroll
      for (int r = 0; r < 4; r++) {
        const float p = __expf(st[jt][r] - m_i[r]);
        csum[r] += p;
        const int prow = quad*4 + r;
        Pw[prow*64 + (((jt*2 + (l16 >> 3)) ^ (prow & 7)) << 3) + l7] = f2bf(p);
      }
#pragma unroll
    for (int r = 0; r < 4; r++) {
      float cs = csum[r];
      cs += __shfl_xor(cs, 1, 64);
      cs += __shfl_xor(cs, 2, 64);
      cs += __shfl_xor(cs, 4, 64);
      cs += __shfl_xor(cs, 8, 64);
      l_i[r] = l_i[r] * alpha[r] + cs;
    }
    if (__any(needresc)) {
#pragma unroll
      for (int r = 0; r < 4; r++)
#pragma unroll
        for (int dt = 0; dt < 8; dt++) Oacc[dt][r] *= alpha[r];
    }

    // ---- O += P * V  (same-wave LDS RAW on Pw; swizzled P and V reads)
    __builtin_amdgcn_s_setprio(1);
#pragma unroll
    for (int ks2 = 0; ks2 < 2; ks2++) {
      frag8 pf = *(const frag8*)&Pw[l16*64 + ((ks2*4 + quad) ^ l7)*8];
#pragma unroll
      for (int dt = 0; dt < 8; dt++) {
        frag8 vf = *(const frag8*)&smem[8192 + (dt*16 + l16)*64 + ((ks2*4 + quad) ^ l7)*8];
        Oacc[dt] = __builtin_amdgcn_mfma_f32_16x16x32_bf16(pf, vf, Oacc[dt], 0, 0, 0);
      }
    }
    __builtin_amdgcn_s_setprio(0);
    __syncthreads();   // protect Ks/Vs before next stage
  }

  // ---- finalize: /l_i, store merged [b*2048+m][h*128+d]
#pragma unroll
  for (int r = 0; r < 4; r++) {
    const float inv = 1.0f / l_i[r];
    const int m = qt*64 + wv*16 + quad*4 + r;
#pragma unroll
    for (int dt = 0; dt < 8; dt++) {
      const int d = dt*16 + l16;
      O[((size_t)(b * SEQ) + m) * HIDDEN + h * HDIM + d] = f2bf(Oacc[dt][r] * inv);
    }
  }
}

// ---------------------------------------------------------------------------
extern "C" void kernel_launch(void* const* d_in, const int* in_sizes, int n_in,
                              void* d_out, int out_size, void* d_ws, size_t ws_size,
                              hipStream_t stream)
{
  const float* X  = (const float*)d_in[0];
  const float* Wq = (const float*)d_in[1];
  const float* bq = (const float*)d_in[2];
  const float* Wk = (const float*)d_in[3];
  const float* bk = (const float*)d_in[4];
  const float* Wv = (const float*)d_in[5];
  const float* bv = (const float*)d_in[6];
  const float* Wo = (const float*)d_in[7];
  const float* bo = (const float*)d_in[8];
  float* out = (float*)d_out;

  u16* Kb = (u16*)d_out;
  u16* Xb = (u16*)d_out + (8u << 20);
  char* ws = (char*)d_ws;
  u16* Qb  = (u16*)ws;
  u16* Vtb = (u16*)(ws + (16u << 20));

  dim3 blk(256);
  const bool fast = ws_size >= (64u << 20);
  if (fast) {
    u16* Wqb = (u16*)(ws + (32u << 20));
    u16* Wkb = (u16*)(ws + (40u << 20));
    u16* Wvb = (u16*)(ws + (48u << 20));
    u16* Wob = (u16*)(ws + (56u << 20));
    cvt_all<<<12288, blk, 0, stream>>>(X, Wq, Wk, Wv, Wo, Xb, Wqb, Wkb, Wvb, Wob);
    gemm256_qkv<<<dim3(768), dim3(512), 0, stream>>>(
        Xb, Wqb, Wkb, Wvb, bq, bk, bv, Qb, Kb, Vtb);
    attn_kernel<<<1024, blk, 0, stream>>>(Qb, Kb, Vtb, Qb);
    gemm256_o<<<dim3(256), dim3(512), 0, stream>>>(Qb, Wob, bo, out);
  } else {
    cvt_all<<<4096, blk, 0, stream>>>(X, Wq, Wk, Wv, Wo, Xb, Xb, Xb, Xb, Xb);
    gemm_fused<0,3,1,0><<<dim3(48,32), blk, 0, stream>>>(
        Xb, Wq, Wk, Wv, bq, bk, bv, Qb, Kb, Vtb);
    rope_kernel<<<4096, blk, 0, stream>>>(Qb, Kb);
    attn_kernel<<<1024, blk, 0, stream>>>(Qb, Kb, Vtb, Qb);
    gemm_fused<0,1,0,1><<<dim3(16,32), blk, 0, stream>>>(
        Qb, Wo, Wo, Wo, bo, bo, bo, out, out, out);
  }
}